// Round 1
// baseline (332.421 us; speedup 1.0000x reference)
//
#include <hip/hip_runtime.h>
#include <math.h>

#define NEG_SLOPE 0.2f
#define EPS_GAT 1e-16f
#define LOG2E 1.4426950408889634f
typedef unsigned int u32;
typedef unsigned short u16;
typedef __attribute__((ext_vector_type(8))) short short8;   // 8 bf16 (4 VGPRs)
typedef __attribute__((ext_vector_type(4))) float f32x4;

// ---- bf16 helpers ----
__device__ inline u16 f2bf(float x) {
    union { float f; u32 u; } v; v.f = x;
    u32 r = v.u + 0x7FFFu + ((v.u >> 16) & 1u);   // RNE
    return (u16)(r >> 16);
}
__device__ inline float bf_lo(u32 u) {
    union { u32 i; float f; } v; v.i = u << 16; return v.f;
}
__device__ inline float bf_hi(u32 u) {
    union { u32 i; float f; } v; v.i = u & 0xFFFF0000u; return v.f;
}
__device__ inline float bf1(u16 s) {
    union { u32 i; float f; } v; v.i = ((u32)s) << 16; return v.f;
}
__device__ inline float fast_exp2(float x) {
#if __has_builtin(__builtin_amdgcn_exp2f)
    return __builtin_amdgcn_exp2f(x);
#else
    return exp2f(x);
#endif
}
// logits pre-scaled by LOG2E; lrelu commutes with positive scaling.
__device__ inline float lrelu_exp2(float t) {
    return fast_exp2(fmaxf(t, NEG_SLOPE * t));
}

// ---------------- CSR degree + (fused) weight prep ----------------
// blocks < degBlocks: degree+rank (one edge per thread). next 64: W1 hi/lo split. last: W2 fold.

__global__ void degree_prep_kernel(const int* __restrict__ dst, int E,
                                   int* __restrict__ counts, int* __restrict__ rank,
                                   const float* __restrict__ W1,
                                   u16* __restrict__ w1t_hi, u16* __restrict__ w1t_lo,
                                   const float* __restrict__ W2, const float* __restrict__ a2s,
                                   const float* __restrict__ a2d, float* __restrict__ w_as,
                                   float* __restrict__ w_ad, int degBlocks) {
    int b = blockIdx.x;
    if (b < degBlocks) {
        int e = b * 256 + threadIdx.x;
        if (e < E) rank[e] = atomicAdd(&counts[dst[e]], 1);
    } else if (b < degBlocks + 64) {
        int i = (b - degBlocks) * 256 + threadIdx.x;   // 16384
        int k = i >> 7, n = i & 127;
        float w = W1[i];
        u16 hi = f2bf(w);
        u16 lo = f2bf(w - bf1(hi));
        w1t_hi[n * 128 + k] = hi;
        w1t_lo[n * 128 + k] = lo;
    } else {
        int t = threadIdx.x;
        if (t < 128) {
            int h = t >> 5, k = t & 31;
            float s1 = 0.f, s2 = 0.f;
#pragma unroll
            for (int f = 0; f < 16; ++f) {
                float w = W2[k * 64 + h * 16 + f];
                s1 += w * a2s[h * 16 + f];
                s2 += w * a2d[h * 16 + f];
            }
            w_as[h * 32 + k] = s1;
            w_ad[h * 32 + k] = s2;
        }
    }
}

__global__ __launch_bounds__(1024) void scan_block_kernel(const int* __restrict__ counts, int N,
                                                          int* __restrict__ scanned, int* __restrict__ bsums) {
    __shared__ int tmp[1024];
    int i = blockIdx.x * 1024 + threadIdx.x;
    int v = (i < N) ? counts[i] : 0;
    tmp[threadIdx.x] = v;
    __syncthreads();
    for (int d = 1; d < 1024; d <<= 1) {
        int t = (threadIdx.x >= d) ? tmp[threadIdx.x - d] : 0;
        __syncthreads();
        tmp[threadIdx.x] += t;
        __syncthreads();
    }
    if (i < N) scanned[i] = tmp[threadIdx.x];
    if (threadIdx.x == 1023) bsums[blockIdx.x] = tmp[1023];
}

__global__ __launch_bounds__(256) void scan_partials_kernel(int* __restrict__ bsums, int nb) {
    __shared__ int tmp[256];
    int tid = threadIdx.x;
    int v = (tid < nb) ? bsums[tid] : 0;
    tmp[tid] = v;
    __syncthreads();
    for (int d = 1; d < 256; d <<= 1) {
        int t = (tid >= d) ? tmp[tid - d] : 0;
        __syncthreads();
        tmp[tid] += t;
        __syncthreads();
    }
    if (tid < nb) bsums[tid] = tmp[tid] - v;  // exclusive
}

__global__ void finalize_offsets_kernel(const int* __restrict__ scanned,
                                        const int* __restrict__ bsums_excl, int N,
                                        int* __restrict__ row_off) {
    int i = blockIdx.x * blockDim.x + threadIdx.x;
    if (i < N) {
        int incl = scanned[i] + bsums_excl[i >> 10];
        row_off[i + 1] = incl;
        if (i == 0) row_off[0] = 0;
    }
}

__global__ void fill_csr_kernel(const int* __restrict__ src, const int* __restrict__ dst, int E,
                                const int* __restrict__ row_off, const int* __restrict__ rank,
                                int* __restrict__ csr_src) {
    int e = blockIdx.x * blockDim.x + threadIdx.x;
    if (e < E) {
        int pos = row_off[dst[e]] + rank[e];
        csr_src[pos] = src[e];
    }
}

// ---------------- GEMM1 via MFMA + fused attn1 epilogue ----------------
// hi/lo split (3 MFMAs) = fp32-grade. After the K-loop, the h-tile is staged in
// LDS (aliasing the W-staging buffer — safe after the final barrier) and one
// thread per (row,head) computes the two 32-dots for as1/ad1 (pre-scaled LOG2E).

__global__ __launch_bounds__(256) void gemm1_mfma_kernel(const float* __restrict__ X,
                                                         const u16* __restrict__ w1t_hi,
                                                         const u16* __restrict__ w1t_lo,
                                                         const float* __restrict__ a_src,
                                                         const float* __restrict__ a_dst,
                                                         u16* __restrict__ Hb,
                                                         float* __restrict__ as_,
                                                         float* __restrict__ ad_, int N) {
    __shared__ u16 xsh_hi[64][40];
    __shared__ u16 xsh_lo[64][40];
    __shared__ u16 wbuf[10240];          // wsh_hi | wsh_lo; reused as h-tile after K-loop
    __shared__ float ash[128], adsh[128];
    u16* wsh_hi = wbuf;
    u16* wsh_lo = wbuf + 5120;
    int tid = threadIdx.x;
    int wave = tid >> 6, lane = tid & 63, quad = lane >> 4;
    int m0 = blockIdx.x * 64;

    if (tid < 128) { ash[tid] = a_src[tid]; adsh[tid] = a_dst[tid]; }

    f32x4 acc[4][2];
#pragma unroll
    for (int rt = 0; rt < 4; ++rt)
#pragma unroll
        for (int ct = 0; ct < 2; ++ct) acc[rt][ct] = (f32x4)(0.f);

    int xrow = tid >> 2, xkq = (tid & 3) * 8;

    for (int k0 = 0; k0 < 128; k0 += 32) {
        {
            int gr = m0 + xrow;
            float f[8];
            *(float4*)&f[0] = (gr < N) ? *(const float4*)(X + (size_t)gr * 128 + k0 + xkq)
                                       : make_float4(0.f, 0.f, 0.f, 0.f);
            *(float4*)&f[4] = (gr < N) ? *(const float4*)(X + (size_t)gr * 128 + k0 + xkq + 4)
                                       : make_float4(0.f, 0.f, 0.f, 0.f);
            u16 hi[8], lo[8];
#pragma unroll
            for (int i = 0; i < 8; ++i) {
                hi[i] = f2bf(f[i]);
                lo[i] = f2bf(f[i] - bf1(hi[i]));
            }
            *(uint4*)&xsh_hi[xrow][xkq] = *(uint4*)hi;
            *(uint4*)&xsh_lo[xrow][xkq] = *(uint4*)lo;
        }
        {
#pragma unroll
            for (int i = 0; i < 2; ++i) {
                int id = tid * 2 + i;
                int n = id >> 2, part = id & 3;
                *(uint4*)&wsh_hi[n * 40 + part * 8] =
                    ((const uint4*)(w1t_hi + n * 128 + k0))[part];
                *(uint4*)&wsh_lo[n * 40 + part * 8] =
                    ((const uint4*)(w1t_lo + n * 128 + k0))[part];
            }
        }
        __syncthreads();

        short8 bhi[2], blo[2];
#pragma unroll
        for (int ct = 0; ct < 2; ++ct) {
            int n = wave * 32 + ct * 16 + (lane & 15);
            bhi[ct] = *(const short8*)&wsh_hi[n * 40 + quad * 8];
            blo[ct] = *(const short8*)&wsh_lo[n * 40 + quad * 8];
        }
#pragma unroll
        for (int rt = 0; rt < 4; ++rt) {
            int m = rt * 16 + (lane & 15);
            short8 ahi = *(const short8*)&xsh_hi[m][quad * 8];
            short8 alo = *(const short8*)&xsh_lo[m][quad * 8];
#pragma unroll
            for (int ct = 0; ct < 2; ++ct) {
                acc[rt][ct] = __builtin_amdgcn_mfma_f32_16x16x32_bf16(ahi, bhi[ct], acc[rt][ct], 0, 0, 0);
                acc[rt][ct] = __builtin_amdgcn_mfma_f32_16x16x32_bf16(alo, bhi[ct], acc[rt][ct], 0, 0, 0);
                acc[rt][ct] = __builtin_amdgcn_mfma_f32_16x16x32_bf16(ahi, blo[ct], acc[rt][ct], 0, 0, 0);
            }
        }
        __syncthreads();
    }

    // h-tile -> global + LDS (stride 130 u16 per row; 16640 B <= 20480 B of wbuf)
    const int HS = 130;
#pragma unroll
    for (int rt = 0; rt < 4; ++rt)
#pragma unroll
        for (int ct = 0; ct < 2; ++ct) {
            int col = wave * 32 + ct * 16 + (lane & 15);
#pragma unroll
            for (int r = 0; r < 4; ++r) {
                int row = rt * 16 + quad * 4 + r;
                u16 hv = f2bf(acc[rt][ct][r]);
                int gr = m0 + row;
                if (gr < N) Hb[(size_t)gr * 128 + col] = hv;
                wbuf[row * HS + col] = hv;
            }
        }
    __syncthreads();

    // attn1: one thread per (row, head)
    {
        int row = tid >> 2, h = tid & 3;
        int gr = m0 + row;
        if (gr < N) {
            const u32* hr = (const u32*)&wbuf[row * HS + h * 32];   // 16 dwords
            float s1 = 0.f, s2 = 0.f;
#pragma unroll
            for (int q = 0; q < 16; ++q) {
                u32 u = hr[q];
                float flo = bf_lo(u), fhi = bf_hi(u);
                s1 += flo * ash[h * 32 + 2 * q] + fhi * ash[h * 32 + 2 * q + 1];
                s2 += flo * adsh[h * 32 + 2 * q] + fhi * adsh[h * 32 + 2 * q + 1];
            }
            as_[(size_t)gr * 4 + h] = s1 * LOG2E;
            ad_[(size_t)gr * 4 + h] = s2 * LOG2E;
        }
    }
}

// ---------------- layer-1 aggregate + fused attn2 epilogue ----------------
// Softmax numerators hoisted out of the edge loop: lane l precomputes
// e(edge q*16+(l&15), head l>>4) for q=0..3 — 4 exps/lane total instead of
// one exp per lane per edge (16x redundant). Denominator = shfl_xor tree of
// those registers. Inner loop fetches e with one ds_bpermute (__shfl).

__global__ __launch_bounds__(256) void node_agg128_kernel(const u32* __restrict__ Hb,
                                                          const float* __restrict__ as_,
                                                          const float* __restrict__ ad_,
                                                          const int* __restrict__ row_off,
                                                          const int* __restrict__ csr_src,
                                                          const float* __restrict__ bias,
                                                          const float* __restrict__ w_as,
                                                          const float* __restrict__ w_ad,
                                                          u32* __restrict__ O1,
                                                          float* __restrict__ as2,
                                                          float* __restrict__ ad2, int N) {
    int lane = threadIdx.x & 63;
    int node = __builtin_amdgcn_readfirstlane(blockIdx.x * 4 + (threadIdx.x >> 6));
    if (node >= N) return;
    int start = __builtin_amdgcn_readfirstlane(row_off[node]);
    int end   = __builtin_amdgcn_readfirstlane(row_off[node + 1]);
    int deg = end - start;
    int h = lane >> 4;
    int r = lane & 15;
    int grpbase = lane & 48;
    float adh = ad_[node * 4 + h];

    int clamp = (deg > 0) ? deg - 1 : 0;
    // deg==0: force a valid index (0) — prologue dereferences as_[src].
    int vidx = (deg > 0) ? csr_src[start + min(lane, clamp)] : 0;
    int m = min(deg, 64);

    // prologue: lane holds e for edges {q*16+r}, own head; masked to 0 past m
    float Pv[4];
#pragma unroll
    for (int q = 0; q < 4; ++q) {
        int eq = q * 16 + r;
        int sq = __shfl(vidx, eq);
        float aq = as_[sq * 4 + h];
        float pe = lrelu_exp2(aq + adh);
        Pv[q] = (eq < m) ? pe : 0.f;
    }
    float den = (Pv[0] + Pv[1]) + (Pv[2] + Pv[3]);
    den += __shfl_xor(den, 1);
    den += __shfl_xor(den, 2);
    den += __shfl_xor(den, 4);
    den += __shfl_xor(den, 8);

    float2 acc = make_float2(0.f, 0.f);
    int j = 0;
#pragma unroll
    for (int q = 0; q < 4; ++q) {
        const int lim = min(m, (q + 1) * 16);
        for (; j + 4 <= lim; j += 4) {
            int s0 = __builtin_amdgcn_readlane(vidx, j);
            int s1 = __builtin_amdgcn_readlane(vidx, j + 1);
            int s2 = __builtin_amdgcn_readlane(vidx, j + 2);
            int s3 = __builtin_amdgcn_readlane(vidx, j + 3);
            float e0 = __shfl(Pv[q], grpbase | (j - q * 16));
            float e1 = __shfl(Pv[q], grpbase | (j + 1 - q * 16));
            float e2 = __shfl(Pv[q], grpbase | (j + 2 - q * 16));
            float e3 = __shfl(Pv[q], grpbase | (j + 3 - q * 16));
            u32 u0 = Hb[(size_t)s0 * 64 + lane];
            u32 u1 = Hb[(size_t)s1 * 64 + lane];
            u32 u2 = Hb[(size_t)s2 * 64 + lane];
            u32 u3 = Hb[(size_t)s3 * 64 + lane];
            acc.x = fmaf(e0, bf_lo(u0), acc.x); acc.y = fmaf(e0, bf_hi(u0), acc.y);
            acc.x = fmaf(e1, bf_lo(u1), acc.x); acc.y = fmaf(e1, bf_hi(u1), acc.y);
            acc.x = fmaf(e2, bf_lo(u2), acc.x); acc.y = fmaf(e2, bf_hi(u2), acc.y);
            acc.x = fmaf(e3, bf_lo(u3), acc.x); acc.y = fmaf(e3, bf_hi(u3), acc.y);
        }
        for (; j < lim; ++j) {
            int s = __builtin_amdgcn_readlane(vidx, j);
            float e = __shfl(Pv[q], grpbase | (j - q * 16));
            u32 u = Hb[(size_t)s * 64 + lane];
            acc.x = fmaf(e, bf_lo(u), acc.x); acc.y = fmaf(e, bf_hi(u), acc.y);
        }
    }
    for (int jj = start + 64; jj < end; ++jj) {   // deg>64 fallback
        int s = __builtin_amdgcn_readfirstlane(csr_src[jj]);
        float e = lrelu_exp2(as_[s * 4 + h] + adh);
        u32 u = Hb[(size_t)s * 64 + lane];
        acc.x = fmaf(e, bf_lo(u), acc.x); acc.y = fmaf(e, bf_hi(u), acc.y); den += e;
    }
    float inv = 1.f / (den + EPS_GAT);
    float px = acc.x * inv, py = acc.y * inv;
    // butterfly head-sum: afterwards EVERY lane holds the 4-head sum for f=lane&15
    px += __shfl_xor(px, 16); py += __shfl_xor(py, 16);
    px += __shfl_xor(px, 32); py += __shfl_xor(py, 32);

    int f2 = (lane & 15) * 2;
    float2 bv = *(const float2*)&bias[f2];
    float ox = fmaxf(px * 0.25f + bv.x, 0.f);
    float oy = fmaxf(py * 0.25f + bv.y, 0.f);
    if (lane < 16)
        O1[node * 16 + lane] = (u32)f2bf(ox) | ((u32)f2bf(oy) << 16);

    // fused attn2 (16-lane xor reduction)
    int h2 = lane >> 4;
    float2 wa = *(const float2*)&w_as[h2 * 32 + f2];
    float2 wd = *(const float2*)&w_ad[h2 * 32 + f2];
    float ta = ox * wa.x + oy * wa.y;
    float td = ox * wd.x + oy * wd.y;
    ta += __shfl_xor(ta, 1); td += __shfl_xor(td, 1);
    ta += __shfl_xor(ta, 2); td += __shfl_xor(td, 2);
    ta += __shfl_xor(ta, 4); td += __shfl_xor(td, 4);
    ta += __shfl_xor(ta, 8); td += __shfl_xor(td, 8);
    if ((lane & 15) == 0) {
        as2[node * 4 + h2] = ta * LOG2E;
        ad2[node * 4 + h2] = td * LOG2E;
    }
}

// ---------------- layer-2 aggregate + fused W2 epilogue ----------------
// No LDS, no barriers: W2 column lives in 32 VGPRs per lane (loaded once per
// wave, coalesced), epilogue is 32 bpermutes + 32 FMA. Grid-stride so the
// W2 preload amortizes over ~12 nodes/wave.

__global__ __launch_bounds__(256) void node_agg32_fused_kernel(const u32* __restrict__ O1,
                                                               const float* __restrict__ as_,
                                                               const float* __restrict__ ad_,
                                                               const int* __restrict__ row_off,
                                                               const int* __restrict__ csr_src,
                                                               const float* __restrict__ W2,
                                                               const float* __restrict__ b2,
                                                               float* __restrict__ Out, int N) {
    int lane = threadIdx.x & 63;
    int h = lane >> 4, f = lane & 15;
    int grpbase = lane & 48;
    int wid = blockIdx.x * 4 + (threadIdx.x >> 6);
    int nw = gridDim.x * 4;

    // per-lane W2 column: wcol[k] = W2[k][h*16+f]  (h*16+f == lane)
    float wcol[32];
#pragma unroll
    for (int k = 0; k < 32; ++k) wcol[k] = W2[k * 64 + lane];
    float bo = b2[f];

    for (int node = wid; node < N; node += nw) {
        int start = __builtin_amdgcn_readfirstlane(row_off[node]);
        int end   = __builtin_amdgcn_readfirstlane(row_off[node + 1]);
        int deg = end - start;
        float adh = ad_[node * 4 + h];

        int clamp = (deg > 0) ? deg - 1 : 0;
        int vidx = (deg > 0) ? csr_src[start + min(lane, clamp)] : 0;
        int m = min(deg, 64);

        float Pv[4];
#pragma unroll
        for (int q = 0; q < 4; ++q) {
            int eq = q * 16 + f;
            int sq = __shfl(vidx, eq);
            float aq = as_[sq * 4 + h];
            float pe = lrelu_exp2(aq + adh);
            Pv[q] = (eq < m) ? pe : 0.f;
        }
        float den = (Pv[0] + Pv[1]) + (Pv[2] + Pv[3]);
        den += __shfl_xor(den, 1);
        den += __shfl_xor(den, 2);
        den += __shfl_xor(den, 4);
        den += __shfl_xor(den, 8);

        float2 acc = make_float2(0.f, 0.f);
        int j = 0;
#pragma unroll
        for (int q = 0; q < 4; ++q) {
            const int lim = min(m, (q + 1) * 16);
            for (; j + 4 <= lim; j += 4) {
                int s0 = __builtin_amdgcn_readlane(vidx, j);
                int s1 = __builtin_amdgcn_readlane(vidx, j + 1);
                int s2 = __builtin_amdgcn_readlane(vidx, j + 2);
                int s3 = __builtin_amdgcn_readlane(vidx, j + 3);
                float e0 = __shfl(Pv[q], grpbase | (j - q * 16));
                float e1 = __shfl(Pv[q], grpbase | (j + 1 - q * 16));
                float e2 = __shfl(Pv[q], grpbase | (j + 2 - q * 16));
                float e3 = __shfl(Pv[q], grpbase | (j + 3 - q * 16));
                u32 u0 = O1[s0 * 16 + f];
                u32 u1 = O1[s1 * 16 + f];
                u32 u2 = O1[s2 * 16 + f];
                u32 u3 = O1[s3 * 16 + f];
                acc.x = fmaf(e0, bf_lo(u0), acc.x); acc.y = fmaf(e0, bf_hi(u0), acc.y);
                acc.x = fmaf(e1, bf_lo(u1), acc.x); acc.y = fmaf(e1, bf_hi(u1), acc.y);
                acc.x = fmaf(e2, bf_lo(u2), acc.x); acc.y = fmaf(e2, bf_hi(u2), acc.y);
                acc.x = fmaf(e3, bf_lo(u3), acc.x); acc.y = fmaf(e3, bf_hi(u3), acc.y);
            }
            for (; j < lim; ++j) {
                int s = __builtin_amdgcn_readlane(vidx, j);
                float e = __shfl(Pv[q], grpbase | (j - q * 16));
                u32 u = O1[s * 16 + f];
                acc.x = fmaf(e, bf_lo(u), acc.x); acc.y = fmaf(e, bf_hi(u), acc.y);
            }
        }
        for (int jj = start + 64; jj < end; ++jj) {
            int s = __builtin_amdgcn_readfirstlane(csr_src[jj]);
            float e = lrelu_exp2(as_[s * 4 + h] + adh);
            u32 u = O1[s * 16 + f];
            acc.x = fmaf(e, bf_lo(u), acc.x); acc.y = fmaf(e, bf_hi(u), acc.y);
            den += e;
        }
        float inv = 1.f / (den + EPS_GAT);
        float px = acc.x * inv, py = acc.y * inv;

        // epilogue: s(h,f) = sum_k agg[h][k] * W2[k][h*16+f] via bpermute broadcast
        float s = 0.f;
#pragma unroll
        for (int k = 0; k < 16; ++k) {
            float vx = __shfl(px, grpbase | k);
            float vy = __shfl(py, grpbase | k);
            s = fmaf(vx, wcol[2 * k], s);
            s = fmaf(vy, wcol[2 * k + 1], s);
        }
        s += __shfl_xor(s, 16);
        s += __shfl_xor(s, 32);
        if (lane < 16)
            Out[(size_t)node * 16 + f] = s * 0.25f + bo;
    }
}

// ---------------- launch ----------------

extern "C" void kernel_launch(void* const* d_in, const int* in_sizes, int n_in,
                              void* d_out, int out_size, void* d_ws, size_t ws_size,
                              hipStream_t stream) {
    const float* x      = (const float*)d_in[0];
    const int*   eidx   = (const int*)d_in[1];
    const float* W1     = (const float*)d_in[2];
    const float* a1_src = (const float*)d_in[3];
    const float* a1_dst = (const float*)d_in[4];
    const float* b1     = (const float*)d_in[5];
    const float* W2     = (const float*)d_in[6];
    const float* a2_src = (const float*)d_in[7];
    const float* a2_dst = (const float*)d_in[8];
    const float* b2     = (const float*)d_in[9];
    float* out = (float*)d_out;

    const int N = in_sizes[0] / 128;
    const int E = in_sizes[1] / 2;
    const int* src = eidx;
    const int* dst = eidx + E;

    char* base = (char*)d_ws;
    size_t off = 0;
    auto carve = [&](size_t bytes) -> char* {
        off = (off + 255) & ~(size_t)255;
        char* p = base + off;
        off += bytes;
        return p;
    };
    int* counts   = (int*)carve((size_t)N * 4);
    int* scanned  = (int*)carve((size_t)N * 4);
    int* bsums    = (int*)carve(256 * 4);
    int* row_off  = (int*)carve((size_t)(N + 1) * 4);
    int* rank     = (int*)carve((size_t)E * 4);
    int* csr_src  = (int*)carve((size_t)E * 4);
    u16* w1t_hi   = (u16*)carve(128 * 128 * 2);
    u16* w1t_lo   = (u16*)carve(128 * 128 * 2);
    u16* h1b      = (u16*)carve((size_t)N * 128 * 2);
    u32* out1b    = (u32*)carve((size_t)N * 16 * 4);
    float* as1  = (float*)carve((size_t)N * 4 * 4);
    float* ad1  = (float*)carve((size_t)N * 4 * 4);
    float* as2  = (float*)carve((size_t)N * 4 * 4);
    float* ad2  = (float*)carve((size_t)N * 4 * 4);
    float* w_as = (float*)carve(4 * 32 * 4);
    float* w_ad = (float*)carve(4 * 32 * 4);
    (void)ws_size; (void)n_in; (void)out_size;

    // --- CSR build + weight prep (fused grid) ---
    hipMemsetAsync(counts, 0, (size_t)N * 4, stream);
    int degBlocks = (E + 255) / 256;
    degree_prep_kernel<<<degBlocks + 65, 256, 0, stream>>>(dst, E, counts, rank,
                                                           W1, w1t_hi, w1t_lo,
                                                           W2, a2_src, a2_dst, w_as, w_ad,
                                                           degBlocks);
    int nb = (N + 1023) / 1024;
    scan_block_kernel<<<nb, 1024, 0, stream>>>(counts, N, scanned, bsums);
    scan_partials_kernel<<<1, 256, 0, stream>>>(bsums, nb);
    finalize_offsets_kernel<<<(N + 255) / 256, 256, 0, stream>>>(scanned, bsums, N, row_off);
    fill_csr_kernel<<<(E + 255) / 256, 256, 0, stream>>>(src, dst, E, row_off, rank, csr_src);

    // --- Layer 1 (GEMM + fused attn1) ---
    gemm1_mfma_kernel<<<(N + 63) / 64, 256, 0, stream>>>(x, w1t_hi, w1t_lo, a1_src, a1_dst,
                                                         h1b, as1, ad1, N);
    node_agg128_kernel<<<(N + 3) / 4, 256, 0, stream>>>((const u32*)h1b, as1, ad1,
                                                        row_off, csr_src, b1, w_as, w_ad,
                                                        out1b, as2, ad2, N);

    // --- Layer 2 (aggregate + fused W2 epilogue) ---
    int agg2Blocks = 2048;
    node_agg32_fused_kernel<<<agg2Blocks, 256, 0, stream>>>(out1b, as2, ad2, row_off,
                                                            csr_src, W2, b2, out, N);
}

// Round 2
// 315.526 us; speedup vs baseline: 1.0535x; 1.0535x over previous
//
#include <hip/hip_runtime.h>
#include <math.h>

#define NEG_SLOPE 0.2f
#define EPS_GAT 1e-16f
#define LOG2E 1.4426950408889634f
typedef unsigned int u32;
typedef unsigned short u16;
typedef __attribute__((ext_vector_type(8))) short short8;   // 8 bf16 (4 VGPRs)
typedef __attribute__((ext_vector_type(4))) float f32x4;

// ---- bf16 helpers ----
__device__ inline u16 f2bf(float x) {
    union { float f; u32 u; } v; v.f = x;
    u32 r = v.u + 0x7FFFu + ((v.u >> 16) & 1u);   // RNE
    return (u16)(r >> 16);
}
__device__ inline float bf_lo(u32 u) {
    union { u32 i; float f; } v; v.i = u << 16; return v.f;
}
__device__ inline float bf_hi(u32 u) {
    union { u32 i; float f; } v; v.i = u & 0xFFFF0000u; return v.f;
}
__device__ inline float bf1(u16 s) {
    union { u32 i; float f; } v; v.i = ((u32)s) << 16; return v.f;
}
__device__ inline float fast_exp2(float x) {
#if __has_builtin(__builtin_amdgcn_exp2f)
    return __builtin_amdgcn_exp2f(x);
#else
    return exp2f(x);
#endif
}
// logits pre-scaled by LOG2E; lrelu commutes with positive scaling.
__device__ inline float lrelu_exp2(float t) {
    return fast_exp2(fmaxf(t, NEG_SLOPE * t));
}

// ---------------- CSR degree + (fused) weight prep ----------------
// blocks < degBlocks: degree+rank (one edge per thread). next 64: W1 hi/lo split. last: W2 fold.

__global__ void degree_prep_kernel(const int* __restrict__ dst, int E,
                                   int* __restrict__ counts, int* __restrict__ rank,
                                   const float* __restrict__ W1,
                                   u16* __restrict__ w1t_hi, u16* __restrict__ w1t_lo,
                                   const float* __restrict__ W2, const float* __restrict__ a2s,
                                   const float* __restrict__ a2d, float* __restrict__ w_as,
                                   float* __restrict__ w_ad, int degBlocks) {
    int b = blockIdx.x;
    if (b < degBlocks) {
        int e = b * 256 + threadIdx.x;
        if (e < E) rank[e] = atomicAdd(&counts[dst[e]], 1);
    } else if (b < degBlocks + 64) {
        int i = (b - degBlocks) * 256 + threadIdx.x;   // 16384
        int k = i >> 7, n = i & 127;
        float w = W1[i];
        u16 hi = f2bf(w);
        u16 lo = f2bf(w - bf1(hi));
        w1t_hi[n * 128 + k] = hi;
        w1t_lo[n * 128 + k] = lo;
    } else {
        int t = threadIdx.x;
        if (t < 128) {
            int h = t >> 5, k = t & 31;
            float s1 = 0.f, s2 = 0.f;
#pragma unroll
            for (int f = 0; f < 16; ++f) {
                float w = W2[k * 64 + h * 16 + f];
                s1 += w * a2s[h * 16 + f];
                s2 += w * a2d[h * 16 + f];
            }
            w_as[h * 32 + k] = s1;
            w_ad[h * 32 + k] = s2;
        }
    }
}

__global__ __launch_bounds__(1024) void scan_block_kernel(const int* __restrict__ counts, int N,
                                                          int* __restrict__ scanned, int* __restrict__ bsums) {
    __shared__ int tmp[1024];
    int i = blockIdx.x * 1024 + threadIdx.x;
    int v = (i < N) ? counts[i] : 0;
    tmp[threadIdx.x] = v;
    __syncthreads();
    for (int d = 1; d < 1024; d <<= 1) {
        int t = (threadIdx.x >= d) ? tmp[threadIdx.x - d] : 0;
        __syncthreads();
        tmp[threadIdx.x] += t;
        __syncthreads();
    }
    if (i < N) scanned[i] = tmp[threadIdx.x];
    if (threadIdx.x == 1023) bsums[blockIdx.x] = tmp[1023];
}

__global__ __launch_bounds__(256) void scan_partials_kernel(int* __restrict__ bsums, int nb) {
    __shared__ int tmp[256];
    int tid = threadIdx.x;
    int v = (tid < nb) ? bsums[tid] : 0;
    tmp[tid] = v;
    __syncthreads();
    for (int d = 1; d < 256; d <<= 1) {
        int t = (tid >= d) ? tmp[tid - d] : 0;
        __syncthreads();
        tmp[tid] += t;
        __syncthreads();
    }
    if (tid < nb) bsums[tid] = tmp[tid] - v;  // exclusive
}

__global__ void finalize_offsets_kernel(const int* __restrict__ scanned,
                                        const int* __restrict__ bsums_excl, int N,
                                        int* __restrict__ row_off) {
    int i = blockIdx.x * blockDim.x + threadIdx.x;
    if (i < N) {
        int incl = scanned[i] + bsums_excl[i >> 10];
        row_off[i + 1] = incl;
        if (i == 0) row_off[0] = 0;
    }
}

__global__ void fill_csr_kernel(const int* __restrict__ src, const int* __restrict__ dst, int E,
                                const int* __restrict__ row_off, const int* __restrict__ rank,
                                int* __restrict__ csr_src) {
    int e = blockIdx.x * blockDim.x + threadIdx.x;
    if (e < E) {
        int pos = row_off[dst[e]] + rank[e];
        csr_src[pos] = src[e];
    }
}

// ---------------- GEMM1 via MFMA + fused attn1 epilogue ----------------
// hi/lo split (3 MFMAs) = fp32-grade. After the K-loop, the h-tile is staged in
// LDS (aliasing the W-staging buffer — safe after the final barrier) and one
// thread per (row,head) computes the two 32-dots for as1/ad1 (pre-scaled LOG2E).

__global__ __launch_bounds__(256) void gemm1_mfma_kernel(const float* __restrict__ X,
                                                         const u16* __restrict__ w1t_hi,
                                                         const u16* __restrict__ w1t_lo,
                                                         const float* __restrict__ a_src,
                                                         const float* __restrict__ a_dst,
                                                         u16* __restrict__ Hb,
                                                         float* __restrict__ as_,
                                                         float* __restrict__ ad_, int N) {
    __shared__ u16 xsh_hi[64][40];
    __shared__ u16 xsh_lo[64][40];
    __shared__ u16 wbuf[10240];          // wsh_hi | wsh_lo; reused as h-tile after K-loop
    __shared__ float ash[128], adsh[128];
    u16* wsh_hi = wbuf;
    u16* wsh_lo = wbuf + 5120;
    int tid = threadIdx.x;
    int wave = tid >> 6, lane = tid & 63, quad = lane >> 4;
    int m0 = blockIdx.x * 64;

    if (tid < 128) { ash[tid] = a_src[tid]; adsh[tid] = a_dst[tid]; }

    f32x4 acc[4][2];
#pragma unroll
    for (int rt = 0; rt < 4; ++rt)
#pragma unroll
        for (int ct = 0; ct < 2; ++ct) acc[rt][ct] = (f32x4)(0.f);

    int xrow = tid >> 2, xkq = (tid & 3) * 8;

    for (int k0 = 0; k0 < 128; k0 += 32) {
        {
            int gr = m0 + xrow;
            float f[8];
            *(float4*)&f[0] = (gr < N) ? *(const float4*)(X + (size_t)gr * 128 + k0 + xkq)
                                       : make_float4(0.f, 0.f, 0.f, 0.f);
            *(float4*)&f[4] = (gr < N) ? *(const float4*)(X + (size_t)gr * 128 + k0 + xkq + 4)
                                       : make_float4(0.f, 0.f, 0.f, 0.f);
            u16 hi[8], lo[8];
#pragma unroll
            for (int i = 0; i < 8; ++i) {
                hi[i] = f2bf(f[i]);
                lo[i] = f2bf(f[i] - bf1(hi[i]));
            }
            *(uint4*)&xsh_hi[xrow][xkq] = *(uint4*)hi;
            *(uint4*)&xsh_lo[xrow][xkq] = *(uint4*)lo;
        }
        {
#pragma unroll
            for (int i = 0; i < 2; ++i) {
                int id = tid * 2 + i;
                int n = id >> 2, part = id & 3;
                *(uint4*)&wsh_hi[n * 40 + part * 8] =
                    ((const uint4*)(w1t_hi + n * 128 + k0))[part];
                *(uint4*)&wsh_lo[n * 40 + part * 8] =
                    ((const uint4*)(w1t_lo + n * 128 + k0))[part];
            }
        }
        __syncthreads();

        short8 bhi[2], blo[2];
#pragma unroll
        for (int ct = 0; ct < 2; ++ct) {
            int n = wave * 32 + ct * 16 + (lane & 15);
            bhi[ct] = *(const short8*)&wsh_hi[n * 40 + quad * 8];
            blo[ct] = *(const short8*)&wsh_lo[n * 40 + quad * 8];
        }
#pragma unroll
        for (int rt = 0; rt < 4; ++rt) {
            int m = rt * 16 + (lane & 15);
            short8 ahi = *(const short8*)&xsh_hi[m][quad * 8];
            short8 alo = *(const short8*)&xsh_lo[m][quad * 8];
#pragma unroll
            for (int ct = 0; ct < 2; ++ct) {
                acc[rt][ct] = __builtin_amdgcn_mfma_f32_16x16x32_bf16(ahi, bhi[ct], acc[rt][ct], 0, 0, 0);
                acc[rt][ct] = __builtin_amdgcn_mfma_f32_16x16x32_bf16(alo, bhi[ct], acc[rt][ct], 0, 0, 0);
                acc[rt][ct] = __builtin_amdgcn_mfma_f32_16x16x32_bf16(ahi, blo[ct], acc[rt][ct], 0, 0, 0);
            }
        }
        __syncthreads();
    }

    // h-tile -> global + LDS (stride 130 u16 per row; 16640 B <= 20480 B of wbuf)
    const int HS = 130;
#pragma unroll
    for (int rt = 0; rt < 4; ++rt)
#pragma unroll
        for (int ct = 0; ct < 2; ++ct) {
            int col = wave * 32 + ct * 16 + (lane & 15);
#pragma unroll
            for (int r = 0; r < 4; ++r) {
                int row = rt * 16 + quad * 4 + r;
                u16 hv = f2bf(acc[rt][ct][r]);
                int gr = m0 + row;
                if (gr < N) Hb[(size_t)gr * 128 + col] = hv;
                wbuf[row * HS + col] = hv;
            }
        }
    __syncthreads();

    // attn1: one thread per (row, head)
    {
        int row = tid >> 2, h = tid & 3;
        int gr = m0 + row;
        if (gr < N) {
            const u32* hr = (const u32*)&wbuf[row * HS + h * 32];   // 16 dwords
            float s1 = 0.f, s2 = 0.f;
#pragma unroll
            for (int q = 0; q < 16; ++q) {
                u32 u = hr[q];
                float flo = bf_lo(u), fhi = bf_hi(u);
                s1 += flo * ash[h * 32 + 2 * q] + fhi * ash[h * 32 + 2 * q + 1];
                s2 += flo * adsh[h * 32 + 2 * q] + fhi * adsh[h * 32 + 2 * q + 1];
            }
            as_[(size_t)gr * 4 + h] = s1 * LOG2E;
            ad_[(size_t)gr * 4 + h] = s2 * LOG2E;
        }
    }
}

// ---------------- layer-1 aggregate + fused attn2 epilogue ----------------
// Softmax numerators hoisted out of the edge loop: lane l precomputes
// e(edge q*16+(l&15), head l>>4) for q=0..3 — 4 exps/lane total instead of
// one exp per lane per edge (16x redundant). Denominator = shfl_xor tree of
// those registers. Inner loop fetches e with one ds_bpermute (__shfl).

__global__ __launch_bounds__(256) void node_agg128_kernel(const u32* __restrict__ Hb,
                                                          const float* __restrict__ as_,
                                                          const float* __restrict__ ad_,
                                                          const int* __restrict__ row_off,
                                                          const int* __restrict__ csr_src,
                                                          const float* __restrict__ bias,
                                                          const float* __restrict__ w_as,
                                                          const float* __restrict__ w_ad,
                                                          u32* __restrict__ O1,
                                                          float* __restrict__ as2,
                                                          float* __restrict__ ad2, int N) {
    int lane = threadIdx.x & 63;
    int node = __builtin_amdgcn_readfirstlane(blockIdx.x * 4 + (threadIdx.x >> 6));
    if (node >= N) return;
    int start = __builtin_amdgcn_readfirstlane(row_off[node]);
    int end   = __builtin_amdgcn_readfirstlane(row_off[node + 1]);
    int deg = end - start;
    int h = lane >> 4;
    int r = lane & 15;
    int grpbase = lane & 48;
    float adh = ad_[node * 4 + h];

    int clamp = (deg > 0) ? deg - 1 : 0;
    // deg==0: force a valid index (0) — prologue dereferences as_[src].
    int vidx = (deg > 0) ? csr_src[start + min(lane, clamp)] : 0;
    int m = min(deg, 64);

    // prologue: lane holds e for edges {q*16+r}, own head; masked to 0 past m
    float Pv[4];
#pragma unroll
    for (int q = 0; q < 4; ++q) {
        int eq = q * 16 + r;
        int sq = __shfl(vidx, eq);
        float aq = as_[sq * 4 + h];
        float pe = lrelu_exp2(aq + adh);
        Pv[q] = (eq < m) ? pe : 0.f;
    }
    float den = (Pv[0] + Pv[1]) + (Pv[2] + Pv[3]);
    den += __shfl_xor(den, 1);
    den += __shfl_xor(den, 2);
    den += __shfl_xor(den, 4);
    den += __shfl_xor(den, 8);

    float2 acc = make_float2(0.f, 0.f);
    int j = 0;
#pragma unroll
    for (int q = 0; q < 4; ++q) {
        const int lim = min(m, (q + 1) * 16);
        for (; j + 4 <= lim; j += 4) {
            int s0 = __builtin_amdgcn_readlane(vidx, j);
            int s1 = __builtin_amdgcn_readlane(vidx, j + 1);
            int s2 = __builtin_amdgcn_readlane(vidx, j + 2);
            int s3 = __builtin_amdgcn_readlane(vidx, j + 3);
            float e0 = __shfl(Pv[q], grpbase | (j - q * 16));
            float e1 = __shfl(Pv[q], grpbase | (j + 1 - q * 16));
            float e2 = __shfl(Pv[q], grpbase | (j + 2 - q * 16));
            float e3 = __shfl(Pv[q], grpbase | (j + 3 - q * 16));
            u32 u0 = Hb[(size_t)s0 * 64 + lane];
            u32 u1 = Hb[(size_t)s1 * 64 + lane];
            u32 u2 = Hb[(size_t)s2 * 64 + lane];
            u32 u3 = Hb[(size_t)s3 * 64 + lane];
            acc.x = fmaf(e0, bf_lo(u0), acc.x); acc.y = fmaf(e0, bf_hi(u0), acc.y);
            acc.x = fmaf(e1, bf_lo(u1), acc.x); acc.y = fmaf(e1, bf_hi(u1), acc.y);
            acc.x = fmaf(e2, bf_lo(u2), acc.x); acc.y = fmaf(e2, bf_hi(u2), acc.y);
            acc.x = fmaf(e3, bf_lo(u3), acc.x); acc.y = fmaf(e3, bf_hi(u3), acc.y);
        }
        for (; j < lim; ++j) {
            int s = __builtin_amdgcn_readlane(vidx, j);
            float e = __shfl(Pv[q], grpbase | (j - q * 16));
            u32 u = Hb[(size_t)s * 64 + lane];
            acc.x = fmaf(e, bf_lo(u), acc.x); acc.y = fmaf(e, bf_hi(u), acc.y);
        }
    }
    for (int jj = start + 64; jj < end; ++jj) {   // deg>64 fallback
        int s = __builtin_amdgcn_readfirstlane(csr_src[jj]);
        float e = lrelu_exp2(as_[s * 4 + h] + adh);
        u32 u = Hb[(size_t)s * 64 + lane];
        acc.x = fmaf(e, bf_lo(u), acc.x); acc.y = fmaf(e, bf_hi(u), acc.y); den += e;
    }
    float inv = 1.f / (den + EPS_GAT);
    float px = acc.x * inv, py = acc.y * inv;
    // butterfly head-sum: afterwards EVERY lane holds the 4-head sum for f=lane&15
    px += __shfl_xor(px, 16); py += __shfl_xor(py, 16);
    px += __shfl_xor(px, 32); py += __shfl_xor(py, 32);

    int f2 = (lane & 15) * 2;
    float2 bv = *(const float2*)&bias[f2];
    float ox = fmaxf(px * 0.25f + bv.x, 0.f);
    float oy = fmaxf(py * 0.25f + bv.y, 0.f);
    if (lane < 16)
        O1[node * 16 + lane] = (u32)f2bf(ox) | ((u32)f2bf(oy) << 16);

    // fused attn2 (16-lane xor reduction)
    int h2 = lane >> 4;
    float2 wa = *(const float2*)&w_as[h2 * 32 + f2];
    float2 wd = *(const float2*)&w_ad[h2 * 32 + f2];
    float ta = ox * wa.x + oy * wa.y;
    float td = ox * wd.x + oy * wd.y;
    ta += __shfl_xor(ta, 1); td += __shfl_xor(td, 1);
    ta += __shfl_xor(ta, 2); td += __shfl_xor(td, 2);
    ta += __shfl_xor(ta, 4); td += __shfl_xor(td, 4);
    ta += __shfl_xor(ta, 8); td += __shfl_xor(td, 8);
    if ((lane & 15) == 0) {
        as2[node * 4 + h2] = ta * LOG2E;
        ad2[node * 4 + h2] = td * LOG2E;
    }
}

// ---------------- layer-2 aggregate + fused W2 epilogue ----------------
// One node per wave (25k short blocks: dynamic load balance + wave churn hides
// the random O1/as_ gather latency — the 2048-block grid-stride variant halved
// occupancy and regressed 62->89us). No LDS, no barriers: W2 column lives in
// 32 VGPRs per lane (coalesced, L1-hit per block), epilogue is 32 bpermutes +
// 32 FMA. Softmax numerators hoisted as in node_agg128.

__global__ __launch_bounds__(256) void node_agg32_fused_kernel(const u32* __restrict__ O1,
                                                               const float* __restrict__ as_,
                                                               const float* __restrict__ ad_,
                                                               const int* __restrict__ row_off,
                                                               const int* __restrict__ csr_src,
                                                               const float* __restrict__ W2,
                                                               const float* __restrict__ b2,
                                                               float* __restrict__ Out, int N) {
    int lane = threadIdx.x & 63;
    int h = lane >> 4, f = lane & 15;
    int grpbase = lane & 48;
    int node = __builtin_amdgcn_readfirstlane(blockIdx.x * 4 + (threadIdx.x >> 6));
    if (node >= N) return;

    // per-lane W2 column: wcol[k] = W2[k][h*16+f]  (h*16+f == lane)
    float wcol[32];
#pragma unroll
    for (int k = 0; k < 32; ++k) wcol[k] = W2[k * 64 + lane];
    float bo = b2[f];

    int start = __builtin_amdgcn_readfirstlane(row_off[node]);
    int end   = __builtin_amdgcn_readfirstlane(row_off[node + 1]);
    int deg = end - start;
    float adh = ad_[node * 4 + h];

    int clamp = (deg > 0) ? deg - 1 : 0;
    int vidx = (deg > 0) ? csr_src[start + min(lane, clamp)] : 0;
    int m = min(deg, 64);

    float Pv[4];
#pragma unroll
    for (int q = 0; q < 4; ++q) {
        int eq = q * 16 + f;
        int sq = __shfl(vidx, eq);
        float aq = as_[sq * 4 + h];
        float pe = lrelu_exp2(aq + adh);
        Pv[q] = (eq < m) ? pe : 0.f;
    }
    float den = (Pv[0] + Pv[1]) + (Pv[2] + Pv[3]);
    den += __shfl_xor(den, 1);
    den += __shfl_xor(den, 2);
    den += __shfl_xor(den, 4);
    den += __shfl_xor(den, 8);

    float2 acc = make_float2(0.f, 0.f);
    int j = 0;
#pragma unroll
    for (int q = 0; q < 4; ++q) {
        const int lim = min(m, (q + 1) * 16);
        for (; j + 4 <= lim; j += 4) {
            int s0 = __builtin_amdgcn_readlane(vidx, j);
            int s1 = __builtin_amdgcn_readlane(vidx, j + 1);
            int s2 = __builtin_amdgcn_readlane(vidx, j + 2);
            int s3 = __builtin_amdgcn_readlane(vidx, j + 3);
            float e0 = __shfl(Pv[q], grpbase | (j - q * 16));
            float e1 = __shfl(Pv[q], grpbase | (j + 1 - q * 16));
            float e2 = __shfl(Pv[q], grpbase | (j + 2 - q * 16));
            float e3 = __shfl(Pv[q], grpbase | (j + 3 - q * 16));
            u32 u0 = O1[s0 * 16 + f];
            u32 u1 = O1[s1 * 16 + f];
            u32 u2 = O1[s2 * 16 + f];
            u32 u3 = O1[s3 * 16 + f];
            acc.x = fmaf(e0, bf_lo(u0), acc.x); acc.y = fmaf(e0, bf_hi(u0), acc.y);
            acc.x = fmaf(e1, bf_lo(u1), acc.x); acc.y = fmaf(e1, bf_hi(u1), acc.y);
            acc.x = fmaf(e2, bf_lo(u2), acc.x); acc.y = fmaf(e2, bf_hi(u2), acc.y);
            acc.x = fmaf(e3, bf_lo(u3), acc.x); acc.y = fmaf(e3, bf_hi(u3), acc.y);
        }
        for (; j < lim; ++j) {
            int s = __builtin_amdgcn_readlane(vidx, j);
            float e = __shfl(Pv[q], grpbase | (j - q * 16));
            u32 u = O1[s * 16 + f];
            acc.x = fmaf(e, bf_lo(u), acc.x); acc.y = fmaf(e, bf_hi(u), acc.y);
        }
    }
    for (int jj = start + 64; jj < end; ++jj) {
        int s = __builtin_amdgcn_readfirstlane(csr_src[jj]);
        float e = lrelu_exp2(as_[s * 4 + h] + adh);
        u32 u = O1[s * 16 + f];
        acc.x = fmaf(e, bf_lo(u), acc.x); acc.y = fmaf(e, bf_hi(u), acc.y);
        den += e;
    }
    float inv = 1.f / (den + EPS_GAT);
    float px = acc.x * inv, py = acc.y * inv;

    // epilogue: s(h,f) = sum_k agg[h][k] * W2[k][h*16+f] via bpermute broadcast
    float s = 0.f;
#pragma unroll
    for (int k = 0; k < 16; ++k) {
        float vx = __shfl(px, grpbase | k);
        float vy = __shfl(py, grpbase | k);
        s = fmaf(vx, wcol[2 * k], s);
        s = fmaf(vy, wcol[2 * k + 1], s);
    }
    s += __shfl_xor(s, 16);
    s += __shfl_xor(s, 32);
    if (lane < 16)
        Out[(size_t)node * 16 + f] = s * 0.25f + bo;
}

// ---------------- launch ----------------

extern "C" void kernel_launch(void* const* d_in, const int* in_sizes, int n_in,
                              void* d_out, int out_size, void* d_ws, size_t ws_size,
                              hipStream_t stream) {
    const float* x      = (const float*)d_in[0];
    const int*   eidx   = (const int*)d_in[1];
    const float* W1     = (const float*)d_in[2];
    const float* a1_src = (const float*)d_in[3];
    const float* a1_dst = (const float*)d_in[4];
    const float* b1     = (const float*)d_in[5];
    const float* W2     = (const float*)d_in[6];
    const float* a2_src = (const float*)d_in[7];
    const float* a2_dst = (const float*)d_in[8];
    const float* b2     = (const float*)d_in[9];
    float* out = (float*)d_out;

    const int N = in_sizes[0] / 128;
    const int E = in_sizes[1] / 2;
    const int* src = eidx;
    const int* dst = eidx + E;

    char* base = (char*)d_ws;
    size_t off = 0;
    auto carve = [&](size_t bytes) -> char* {
        off = (off + 255) & ~(size_t)255;
        char* p = base + off;
        off += bytes;
        return p;
    };
    int* counts   = (int*)carve((size_t)N * 4);
    int* scanned  = (int*)carve((size_t)N * 4);
    int* bsums    = (int*)carve(256 * 4);
    int* row_off  = (int*)carve((size_t)(N + 1) * 4);
    int* rank     = (int*)carve((size_t)E * 4);
    int* csr_src  = (int*)carve((size_t)E * 4);
    u16* w1t_hi   = (u16*)carve(128 * 128 * 2);
    u16* w1t_lo   = (u16*)carve(128 * 128 * 2);
    u16* h1b      = (u16*)carve((size_t)N * 128 * 2);
    u32* out1b    = (u32*)carve((size_t)N * 16 * 4);
    float* as1  = (float*)carve((size_t)N * 4 * 4);
    float* ad1  = (float*)carve((size_t)N * 4 * 4);
    float* as2  = (float*)carve((size_t)N * 4 * 4);
    float* ad2  = (float*)carve((size_t)N * 4 * 4);
    float* w_as = (float*)carve(4 * 32 * 4);
    float* w_ad = (float*)carve(4 * 32 * 4);
    (void)ws_size; (void)n_in; (void)out_size;

    // --- CSR build + weight prep (fused grid) ---
    hipMemsetAsync(counts, 0, (size_t)N * 4, stream);
    int degBlocks = (E + 255) / 256;
    degree_prep_kernel<<<degBlocks + 65, 256, 0, stream>>>(dst, E, counts, rank,
                                                           W1, w1t_hi, w1t_lo,
                                                           W2, a2_src, a2_dst, w_as, w_ad,
                                                           degBlocks);
    int nb = (N + 1023) / 1024;
    scan_block_kernel<<<nb, 1024, 0, stream>>>(counts, N, scanned, bsums);
    scan_partials_kernel<<<1, 256, 0, stream>>>(bsums, nb);
    finalize_offsets_kernel<<<(N + 255) / 256, 256, 0, stream>>>(scanned, bsums, N, row_off);
    fill_csr_kernel<<<(E + 255) / 256, 256, 0, stream>>>(src, dst, E, row_off, rank, csr_src);

    // --- Layer 1 (GEMM + fused attn1) ---
    gemm1_mfma_kernel<<<(N + 63) / 64, 256, 0, stream>>>(x, w1t_hi, w1t_lo, a1_src, a1_dst,
                                                         h1b, as1, ad1, N);
    node_agg128_kernel<<<(N + 3) / 4, 256, 0, stream>>>((const u32*)h1b, as1, ad1,
                                                        row_off, csr_src, b1, w_as, w_ad,
                                                        out1b, as2, ad2, N);

    // --- Layer 2 (aggregate + fused W2 epilogue) ---
    node_agg32_fused_kernel<<<(N + 3) / 4, 256, 0, stream>>>(out1b, as2, ad2, row_off,
                                                             csr_src, W2, b2, out, N);
}

// Round 3
// 311.410 us; speedup vs baseline: 1.0675x; 1.0132x over previous
//
#include <hip/hip_runtime.h>
#include <math.h>

#define NEG_SLOPE 0.2f
#define EPS_GAT 1e-16f
#define LOG2E 1.4426950408889634f
typedef unsigned int u32;
typedef unsigned short u16;
typedef __attribute__((ext_vector_type(8))) short short8;   // 8 bf16 (4 VGPRs)
typedef __attribute__((ext_vector_type(4))) float f32x4;

// ---- bf16 helpers ----
__device__ inline u16 f2bf(float x) {
    union { float f; u32 u; } v; v.f = x;
    u32 r = v.u + 0x7FFFu + ((v.u >> 16) & 1u);   // RNE
    return (u16)(r >> 16);
}
__device__ inline float bf_lo(u32 u) {
    union { u32 i; float f; } v; v.i = u << 16; return v.f;
}
__device__ inline float bf_hi(u32 u) {
    union { u32 i; float f; } v; v.i = u & 0xFFFF0000u; return v.f;
}
__device__ inline float bf1(u16 s) {
    union { u32 i; float f; } v; v.i = ((u32)s) << 16; return v.f;
}
__device__ inline float fast_exp2(float x) {
#if __has_builtin(__builtin_amdgcn_exp2f)
    return __builtin_amdgcn_exp2f(x);
#else
    return exp2f(x);
#endif
}
// logits pre-scaled by LOG2E; lrelu commutes with positive scaling.
__device__ inline float lrelu_exp2(float t) {
    return fast_exp2(fmaxf(t, NEG_SLOPE * t));
}

// ---------------- CSR degree + (fused) weight prep ----------------
// blocks < degBlocks: degree+rank (one edge per thread). next 64: W1 hi/lo split. last: W2 fold.

__global__ void degree_prep_kernel(const int* __restrict__ dst, int E,
                                   int* __restrict__ counts, int* __restrict__ rank,
                                   const float* __restrict__ W1,
                                   u16* __restrict__ w1t_hi, u16* __restrict__ w1t_lo,
                                   const float* __restrict__ W2, const float* __restrict__ a2s,
                                   const float* __restrict__ a2d, float* __restrict__ w_as,
                                   float* __restrict__ w_ad, int degBlocks) {
    int b = blockIdx.x;
    if (b < degBlocks) {
        int e = b * 256 + threadIdx.x;
        if (e < E) rank[e] = atomicAdd(&counts[dst[e]], 1);
    } else if (b < degBlocks + 64) {
        int i = (b - degBlocks) * 256 + threadIdx.x;   // 16384
        int k = i >> 7, n = i & 127;
        float w = W1[i];
        u16 hi = f2bf(w);
        u16 lo = f2bf(w - bf1(hi));
        w1t_hi[n * 128 + k] = hi;
        w1t_lo[n * 128 + k] = lo;
    } else {
        int t = threadIdx.x;
        if (t < 128) {
            int h = t >> 5, k = t & 31;
            float s1 = 0.f, s2 = 0.f;
#pragma unroll
            for (int f = 0; f < 16; ++f) {
                float w = W2[k * 64 + h * 16 + f];
                s1 += w * a2s[h * 16 + f];
                s2 += w * a2d[h * 16 + f];
            }
            w_as[h * 32 + k] = s1;
            w_ad[h * 32 + k] = s2;
        }
    }
}

__global__ __launch_bounds__(1024) void scan_block_kernel(const int* __restrict__ counts, int N,
                                                          int* __restrict__ scanned, int* __restrict__ bsums) {
    __shared__ int tmp[1024];
    int i = blockIdx.x * 1024 + threadIdx.x;
    int v = (i < N) ? counts[i] : 0;
    tmp[threadIdx.x] = v;
    __syncthreads();
    for (int d = 1; d < 1024; d <<= 1) {
        int t = (threadIdx.x >= d) ? tmp[threadIdx.x - d] : 0;
        __syncthreads();
        tmp[threadIdx.x] += t;
        __syncthreads();
    }
    if (i < N) scanned[i] = tmp[threadIdx.x];
    if (threadIdx.x == 1023) bsums[blockIdx.x] = tmp[1023];
}

__global__ __launch_bounds__(256) void scan_partials_kernel(int* __restrict__ bsums, int nb) {
    __shared__ int tmp[256];
    int tid = threadIdx.x;
    int v = (tid < nb) ? bsums[tid] : 0;
    tmp[tid] = v;
    __syncthreads();
    for (int d = 1; d < 256; d <<= 1) {
        int t = (tid >= d) ? tmp[tid - d] : 0;
        __syncthreads();
        tmp[tid] += t;
        __syncthreads();
    }
    if (tid < nb) bsums[tid] = tmp[tid] - v;  // exclusive
}

__global__ void finalize_offsets_kernel(const int* __restrict__ scanned,
                                        const int* __restrict__ bsums_excl, int N,
                                        int* __restrict__ row_off) {
    int i = blockIdx.x * blockDim.x + threadIdx.x;
    if (i < N) {
        int incl = scanned[i] + bsums_excl[i >> 10];
        row_off[i + 1] = incl;
        if (i == 0) row_off[0] = 0;
    }
}

__global__ void fill_csr_kernel(const int* __restrict__ src, const int* __restrict__ dst, int E,
                                const int* __restrict__ row_off, const int* __restrict__ rank,
                                int* __restrict__ csr_src) {
    int e = blockIdx.x * blockDim.x + threadIdx.x;
    if (e < E) {
        int pos = row_off[dst[e]] + rank[e];
        csr_src[pos] = src[e];
    }
}

// ---------------- GEMM1 via MFMA + fused attn1 epilogue ----------------
// hi/lo split (3 MFMAs) = fp32-grade. After the K-loop, the h-tile is staged in
// LDS (aliasing the W-staging buffer — safe after the final barrier) and one
// thread per (row,head) computes the two 32-dots for as1/ad1 (pre-scaled LOG2E).

__global__ __launch_bounds__(256) void gemm1_mfma_kernel(const float* __restrict__ X,
                                                         const u16* __restrict__ w1t_hi,
                                                         const u16* __restrict__ w1t_lo,
                                                         const float* __restrict__ a_src,
                                                         const float* __restrict__ a_dst,
                                                         u16* __restrict__ Hb,
                                                         float* __restrict__ as_,
                                                         float* __restrict__ ad_, int N) {
    __shared__ u16 xsh_hi[64][40];
    __shared__ u16 xsh_lo[64][40];
    __shared__ u16 wbuf[10240];          // wsh_hi | wsh_lo; reused as h-tile after K-loop
    __shared__ float ash[128], adsh[128];
    u16* wsh_hi = wbuf;
    u16* wsh_lo = wbuf + 5120;
    int tid = threadIdx.x;
    int wave = tid >> 6, lane = tid & 63, quad = lane >> 4;
    int m0 = blockIdx.x * 64;

    if (tid < 128) { ash[tid] = a_src[tid]; adsh[tid] = a_dst[tid]; }

    f32x4 acc[4][2];
#pragma unroll
    for (int rt = 0; rt < 4; ++rt)
#pragma unroll
        for (int ct = 0; ct < 2; ++ct) acc[rt][ct] = (f32x4)(0.f);

    int xrow = tid >> 2, xkq = (tid & 3) * 8;

    for (int k0 = 0; k0 < 128; k0 += 32) {
        {
            int gr = m0 + xrow;
            float f[8];
            *(float4*)&f[0] = (gr < N) ? *(const float4*)(X + (size_t)gr * 128 + k0 + xkq)
                                       : make_float4(0.f, 0.f, 0.f, 0.f);
            *(float4*)&f[4] = (gr < N) ? *(const float4*)(X + (size_t)gr * 128 + k0 + xkq + 4)
                                       : make_float4(0.f, 0.f, 0.f, 0.f);
            u16 hi[8], lo[8];
#pragma unroll
            for (int i = 0; i < 8; ++i) {
                hi[i] = f2bf(f[i]);
                lo[i] = f2bf(f[i] - bf1(hi[i]));
            }
            *(uint4*)&xsh_hi[xrow][xkq] = *(uint4*)hi;
            *(uint4*)&xsh_lo[xrow][xkq] = *(uint4*)lo;
        }
        {
#pragma unroll
            for (int i = 0; i < 2; ++i) {
                int id = tid * 2 + i;
                int n = id >> 2, part = id & 3;
                *(uint4*)&wsh_hi[n * 40 + part * 8] =
                    ((const uint4*)(w1t_hi + n * 128 + k0))[part];
                *(uint4*)&wsh_lo[n * 40 + part * 8] =
                    ((const uint4*)(w1t_lo + n * 128 + k0))[part];
            }
        }
        __syncthreads();

        short8 bhi[2], blo[2];
#pragma unroll
        for (int ct = 0; ct < 2; ++ct) {
            int n = wave * 32 + ct * 16 + (lane & 15);
            bhi[ct] = *(const short8*)&wsh_hi[n * 40 + quad * 8];
            blo[ct] = *(const short8*)&wsh_lo[n * 40 + quad * 8];
        }
#pragma unroll
        for (int rt = 0; rt < 4; ++rt) {
            int m = rt * 16 + (lane & 15);
            short8 ahi = *(const short8*)&xsh_hi[m][quad * 8];
            short8 alo = *(const short8*)&xsh_lo[m][quad * 8];
#pragma unroll
            for (int ct = 0; ct < 2; ++ct) {
                acc[rt][ct] = __builtin_amdgcn_mfma_f32_16x16x32_bf16(ahi, bhi[ct], acc[rt][ct], 0, 0, 0);
                acc[rt][ct] = __builtin_amdgcn_mfma_f32_16x16x32_bf16(alo, bhi[ct], acc[rt][ct], 0, 0, 0);
                acc[rt][ct] = __builtin_amdgcn_mfma_f32_16x16x32_bf16(ahi, blo[ct], acc[rt][ct], 0, 0, 0);
            }
        }
        __syncthreads();
    }

    // h-tile -> global + LDS (stride 130 u16 per row; 16640 B <= 20480 B of wbuf)
    const int HS = 130;
#pragma unroll
    for (int rt = 0; rt < 4; ++rt)
#pragma unroll
        for (int ct = 0; ct < 2; ++ct) {
            int col = wave * 32 + ct * 16 + (lane & 15);
#pragma unroll
            for (int r = 0; r < 4; ++r) {
                int row = rt * 16 + quad * 4 + r;
                u16 hv = f2bf(acc[rt][ct][r]);
                int gr = m0 + row;
                if (gr < N) Hb[(size_t)gr * 128 + col] = hv;
                wbuf[row * HS + col] = hv;
            }
        }
    __syncthreads();

    // attn1: one thread per (row, head)
    {
        int row = tid >> 2, h = tid & 3;
        int gr = m0 + row;
        if (gr < N) {
            const u32* hr = (const u32*)&wbuf[row * HS + h * 32];   // 16 dwords
            float s1 = 0.f, s2 = 0.f;
#pragma unroll
            for (int q = 0; q < 16; ++q) {
                u32 u = hr[q];
                float flo = bf_lo(u), fhi = bf_hi(u);
                s1 += flo * ash[h * 32 + 2 * q] + fhi * ash[h * 32 + 2 * q + 1];
                s2 += flo * adsh[h * 32 + 2 * q] + fhi * adsh[h * 32 + 2 * q + 1];
            }
            as_[(size_t)gr * 4 + h] = s1 * LOG2E;
            ad_[(size_t)gr * 4 + h] = s2 * LOG2E;
        }
    }
}

// ---------------- layer-1 aggregate + fused attn2 epilogue ----------------
// Latency-chain fix: deg<=16 covers ~97% of nodes (Poisson-10). Fast path
// issues ALL edge gathers up-front in fixed 8-batches (clamped indices are
// valid; Pv=0 masks them) — MLP 8-16 outstanding loads/wave, and the Hb
// gathers (vidx-dependent) overlap the as_-gather->exp chain (Pv-dependent).
// Prologue needs only ONE exp + one as_ gather; Pv[1..3] only when deg>16.

__global__ __launch_bounds__(256) void node_agg128_kernel(const u32* __restrict__ Hb,
                                                          const float* __restrict__ as_,
                                                          const float* __restrict__ ad_,
                                                          const int* __restrict__ row_off,
                                                          const int* __restrict__ csr_src,
                                                          const float* __restrict__ bias,
                                                          const float* __restrict__ w_as,
                                                          const float* __restrict__ w_ad,
                                                          u32* __restrict__ O1,
                                                          float* __restrict__ as2,
                                                          float* __restrict__ ad2, int N) {
    int lane = threadIdx.x & 63;
    int node = __builtin_amdgcn_readfirstlane(blockIdx.x * 4 + (threadIdx.x >> 6));
    if (node >= N) return;
    int start = __builtin_amdgcn_readfirstlane(row_off[node]);
    int end   = __builtin_amdgcn_readfirstlane(row_off[node + 1]);
    int deg = end - start;
    int h = lane >> 4;
    int r = lane & 15;
    int grpbase = lane & 48;
    float adh = ad_[node * 4 + h];

    int clamp = (deg > 0) ? deg - 1 : 0;
    // deg==0: force a valid index (0) — prologue dereferences as_[src].
    int vidx = (deg > 0) ? csr_src[start + min(lane, clamp)] : 0;
    int m = min(deg, 64);

    // prologue: lane holds e(edge r, head h); masked to 0 past m
    float Pv0;
    {
        int sq = __shfl(vidx, r);
        float aq = as_[sq * 4 + h];
        float pe = lrelu_exp2(aq + adh);
        Pv0 = (r < m) ? pe : 0.f;
    }
    float den = Pv0;
    den += __shfl_xor(den, 1);
    den += __shfl_xor(den, 2);
    den += __shfl_xor(den, 4);
    den += __shfl_xor(den, 8);

    float2 acc = make_float2(0.f, 0.f);

#define AGG128_BLK8(J0)                                                           \
    {                                                                             \
        int sj[8]; u32 uj[8];                                                     \
        _Pragma("unroll") for (int j = 0; j < 8; ++j)                             \
            sj[j] = __builtin_amdgcn_readlane(vidx, (J0) + j);                    \
        _Pragma("unroll") for (int j = 0; j < 8; ++j)                             \
            uj[j] = Hb[(size_t)sj[j] * 64 + lane];                                \
        _Pragma("unroll") for (int j = 0; j < 8; ++j) {                           \
            float e = __shfl(Pv0, grpbase | ((J0) + j));                          \
            acc.x = fmaf(e, bf_lo(uj[j]), acc.x);                                 \
            acc.y = fmaf(e, bf_hi(uj[j]), acc.y);                                 \
        }                                                                         \
    }

    if (m <= 8) {
        AGG128_BLK8(0)
    } else if (m <= 16) {
        AGG128_BLK8(0)
        AGG128_BLK8(8)
    } else {
        // general path (deg>16, ~2.6% of nodes): full Pv[0..3] + tail
        float Pv[4];
        Pv[0] = Pv0;
#pragma unroll
        for (int q = 1; q < 4; ++q) {
            int eq = q * 16 + r;
            int sq = __shfl(vidx, eq);
            float aq = as_[sq * 4 + h];
            float pe = lrelu_exp2(aq + adh);
            Pv[q] = (eq < m) ? pe : 0.f;
        }
        float d2 = Pv[1] + Pv[2] + Pv[3];
        d2 += __shfl_xor(d2, 1);
        d2 += __shfl_xor(d2, 2);
        d2 += __shfl_xor(d2, 4);
        d2 += __shfl_xor(d2, 8);
        den += d2;

        int j = 0;
#pragma unroll
        for (int q = 0; q < 4; ++q) {
            const int lim = min(m, (q + 1) * 16);
            for (; j + 4 <= lim; j += 4) {
                int s0 = __builtin_amdgcn_readlane(vidx, j);
                int s1 = __builtin_amdgcn_readlane(vidx, j + 1);
                int s2 = __builtin_amdgcn_readlane(vidx, j + 2);
                int s3 = __builtin_amdgcn_readlane(vidx, j + 3);
                float e0 = __shfl(Pv[q], grpbase | (j - q * 16));
                float e1 = __shfl(Pv[q], grpbase | (j + 1 - q * 16));
                float e2 = __shfl(Pv[q], grpbase | (j + 2 - q * 16));
                float e3 = __shfl(Pv[q], grpbase | (j + 3 - q * 16));
                u32 u0 = Hb[(size_t)s0 * 64 + lane];
                u32 u1 = Hb[(size_t)s1 * 64 + lane];
                u32 u2 = Hb[(size_t)s2 * 64 + lane];
                u32 u3 = Hb[(size_t)s3 * 64 + lane];
                acc.x = fmaf(e0, bf_lo(u0), acc.x); acc.y = fmaf(e0, bf_hi(u0), acc.y);
                acc.x = fmaf(e1, bf_lo(u1), acc.x); acc.y = fmaf(e1, bf_hi(u1), acc.y);
                acc.x = fmaf(e2, bf_lo(u2), acc.x); acc.y = fmaf(e2, bf_hi(u2), acc.y);
                acc.x = fmaf(e3, bf_lo(u3), acc.x); acc.y = fmaf(e3, bf_hi(u3), acc.y);
            }
            for (; j < lim; ++j) {
                int s = __builtin_amdgcn_readlane(vidx, j);
                float e = __shfl(Pv[q], grpbase | (j - q * 16));
                u32 u = Hb[(size_t)s * 64 + lane];
                acc.x = fmaf(e, bf_lo(u), acc.x); acc.y = fmaf(e, bf_hi(u), acc.y);
            }
        }
        for (int jj = start + 64; jj < end; ++jj) {   // deg>64 fallback
            int s = __builtin_amdgcn_readfirstlane(csr_src[jj]);
            float e = lrelu_exp2(as_[s * 4 + h] + adh);
            u32 u = Hb[(size_t)s * 64 + lane];
            acc.x = fmaf(e, bf_lo(u), acc.x); acc.y = fmaf(e, bf_hi(u), acc.y); den += e;
        }
    }
#undef AGG128_BLK8

    float inv = 1.f / (den + EPS_GAT);
    float px = acc.x * inv, py = acc.y * inv;
    // butterfly head-sum: afterwards EVERY lane holds the 4-head sum for f=lane&15
    px += __shfl_xor(px, 16); py += __shfl_xor(py, 16);
    px += __shfl_xor(px, 32); py += __shfl_xor(py, 32);

    int f2 = (lane & 15) * 2;
    float2 bv = *(const float2*)&bias[f2];
    float ox = fmaxf(px * 0.25f + bv.x, 0.f);
    float oy = fmaxf(py * 0.25f + bv.y, 0.f);
    if (lane < 16)
        O1[node * 16 + lane] = (u32)f2bf(ox) | ((u32)f2bf(oy) << 16);

    // fused attn2 (16-lane xor reduction)
    int h2 = lane >> 4;
    float2 wa = *(const float2*)&w_as[h2 * 32 + f2];
    float2 wd = *(const float2*)&w_ad[h2 * 32 + f2];
    float ta = ox * wa.x + oy * wa.y;
    float td = ox * wd.x + oy * wd.y;
    ta += __shfl_xor(ta, 1); td += __shfl_xor(td, 1);
    ta += __shfl_xor(ta, 2); td += __shfl_xor(td, 2);
    ta += __shfl_xor(ta, 4); td += __shfl_xor(td, 4);
    ta += __shfl_xor(ta, 8); td += __shfl_xor(td, 8);
    if ((lane & 15) == 0) {
        as2[node * 4 + h2] = ta * LOG2E;
        ad2[node * 4 + h2] = td * LOG2E;
    }
}

// ---------------- layer-2 aggregate + fused W2 epilogue ----------------
// Same fast-path structure as node_agg128. W2 staged in LDS (8KB, one barrier
// BEFORE the node>=N return — keeps VGPR under the 64-reg occupancy cliff vs
// the 32-VGPR wcol variant). Epilogue: stride-1 ds_reads (2-way = conflict-free).

__global__ __launch_bounds__(256) void node_agg32_fused_kernel(const u32* __restrict__ O1,
                                                               const float* __restrict__ as_,
                                                               const float* __restrict__ ad_,
                                                               const int* __restrict__ row_off,
                                                               const int* __restrict__ csr_src,
                                                               const float* __restrict__ W2,
                                                               const float* __restrict__ b2,
                                                               float* __restrict__ Out, int N) {
    __shared__ float w2sh[2048];        // W2 [32][64]
    int tid = threadIdx.x;
    {
        float4 v = ((const float4*)W2)[tid];
        *(float4*)&w2sh[tid * 4] = v;
        float4 v2 = ((const float4*)W2)[tid + 256];
        *(float4*)&w2sh[(tid + 256) * 4] = v2;
    }
    __syncthreads();

    int lane = tid & 63;
    int h = lane >> 4, f = lane & 15;
    int grpbase = lane & 48;
    int node = __builtin_amdgcn_readfirstlane(blockIdx.x * 4 + (tid >> 6));
    if (node >= N) return;

    int start = __builtin_amdgcn_readfirstlane(row_off[node]);
    int end   = __builtin_amdgcn_readfirstlane(row_off[node + 1]);
    int deg = end - start;
    float adh = ad_[node * 4 + h];

    int clamp = (deg > 0) ? deg - 1 : 0;
    int vidx = (deg > 0) ? csr_src[start + min(lane, clamp)] : 0;
    int m = min(deg, 64);

    float Pv0;
    {
        int sq = __shfl(vidx, f);
        float aq = as_[sq * 4 + h];
        float pe = lrelu_exp2(aq + adh);
        Pv0 = (f < m) ? pe : 0.f;
    }
    float den = Pv0;
    den += __shfl_xor(den, 1);
    den += __shfl_xor(den, 2);
    den += __shfl_xor(den, 4);
    den += __shfl_xor(den, 8);

    float2 acc = make_float2(0.f, 0.f);

#define AGG32_BLK8(J0)                                                            \
    {                                                                             \
        int sj[8]; u32 uj[8];                                                     \
        _Pragma("unroll") for (int j = 0; j < 8; ++j)                             \
            sj[j] = __builtin_amdgcn_readlane(vidx, (J0) + j);                    \
        _Pragma("unroll") for (int j = 0; j < 8; ++j)                             \
            uj[j] = O1[(size_t)sj[j] * 16 + f];                                   \
        _Pragma("unroll") for (int j = 0; j < 8; ++j) {                           \
            float e = __shfl(Pv0, grpbase | ((J0) + j));                          \
            acc.x = fmaf(e, bf_lo(uj[j]), acc.x);                                 \
            acc.y = fmaf(e, bf_hi(uj[j]), acc.y);                                 \
        }                                                                         \
    }

    if (m <= 8) {
        AGG32_BLK8(0)
    } else if (m <= 16) {
        AGG32_BLK8(0)
        AGG32_BLK8(8)
    } else {
        float Pv[4];
        Pv[0] = Pv0;
#pragma unroll
        for (int q = 1; q < 4; ++q) {
            int eq = q * 16 + f;
            int sq = __shfl(vidx, eq);
            float aq = as_[sq * 4 + h];
            float pe = lrelu_exp2(aq + adh);
            Pv[q] = (eq < m) ? pe : 0.f;
        }
        float d2 = Pv[1] + Pv[2] + Pv[3];
        d2 += __shfl_xor(d2, 1);
        d2 += __shfl_xor(d2, 2);
        d2 += __shfl_xor(d2, 4);
        d2 += __shfl_xor(d2, 8);
        den += d2;

        int j = 0;
#pragma unroll
        for (int q = 0; q < 4; ++q) {
            const int lim = min(m, (q + 1) * 16);
            for (; j + 4 <= lim; j += 4) {
                int s0 = __builtin_amdgcn_readlane(vidx, j);
                int s1 = __builtin_amdgcn_readlane(vidx, j + 1);
                int s2 = __builtin_amdgcn_readlane(vidx, j + 2);
                int s3 = __builtin_amdgcn_readlane(vidx, j + 3);
                float e0 = __shfl(Pv[q], grpbase | (j - q * 16));
                float e1 = __shfl(Pv[q], grpbase | (j + 1 - q * 16));
                float e2 = __shfl(Pv[q], grpbase | (j + 2 - q * 16));
                float e3 = __shfl(Pv[q], grpbase | (j + 3 - q * 16));
                u32 u0 = O1[s0 * 16 + f];
                u32 u1 = O1[s1 * 16 + f];
                u32 u2 = O1[s2 * 16 + f];
                u32 u3 = O1[s3 * 16 + f];
                acc.x = fmaf(e0, bf_lo(u0), acc.x); acc.y = fmaf(e0, bf_hi(u0), acc.y);
                acc.x = fmaf(e1, bf_lo(u1), acc.x); acc.y = fmaf(e1, bf_hi(u1), acc.y);
                acc.x = fmaf(e2, bf_lo(u2), acc.x); acc.y = fmaf(e2, bf_hi(u2), acc.y);
                acc.x = fmaf(e3, bf_lo(u3), acc.x); acc.y = fmaf(e3, bf_hi(u3), acc.y);
            }
            for (; j < lim; ++j) {
                int s = __builtin_amdgcn_readlane(vidx, j);
                float e = __shfl(Pv[q], grpbase | (j - q * 16));
                u32 u = O1[s * 16 + f];
                acc.x = fmaf(e, bf_lo(u), acc.x); acc.y = fmaf(e, bf_hi(u), acc.y);
            }
        }
        for (int jj = start + 64; jj < end; ++jj) {
            int s = __builtin_amdgcn_readfirstlane(csr_src[jj]);
            float e = lrelu_exp2(as_[s * 4 + h] + adh);
            u32 u = O1[s * 16 + f];
            acc.x = fmaf(e, bf_lo(u), acc.x); acc.y = fmaf(e, bf_hi(u), acc.y);
            den += e;
        }
    }
#undef AGG32_BLK8

    float inv = 1.f / (den + EPS_GAT);
    float px = acc.x * inv, py = acc.y * inv;

    // epilogue: s(h,f) = sum_k agg[h][k] * W2[k][h*16+f] via bpermute broadcast
    float s = 0.f;
#pragma unroll
    for (int k = 0; k < 16; ++k) {
        float vx = __shfl(px, grpbase | k);
        float vy = __shfl(py, grpbase | k);
        s = fmaf(vx, w2sh[(2 * k) * 64 + lane], s);
        s = fmaf(vy, w2sh[(2 * k + 1) * 64 + lane], s);
    }
    s += __shfl_xor(s, 16);
    s += __shfl_xor(s, 32);
    if (lane < 16)
        Out[(size_t)node * 16 + f] = s * 0.25f + b2[f];
}

// ---------------- launch ----------------

extern "C" void kernel_launch(void* const* d_in, const int* in_sizes, int n_in,
                              void* d_out, int out_size, void* d_ws, size_t ws_size,
                              hipStream_t stream) {
    const float* x      = (const float*)d_in[0];
    const int*   eidx   = (const int*)d_in[1];
    const float* W1     = (const float*)d_in[2];
    const float* a1_src = (const float*)d_in[3];
    const float* a1_dst = (const float*)d_in[4];
    const float* b1     = (const float*)d_in[5];
    const float* W2     = (const float*)d_in[6];
    const float* a2_src = (const float*)d_in[7];
    const float* a2_dst = (const float*)d_in[8];
    const float* b2     = (const float*)d_in[9];
    float* out = (float*)d_out;

    const int N = in_sizes[0] / 128;
    const int E = in_sizes[1] / 2;
    const int* src = eidx;
    const int* dst = eidx + E;

    char* base = (char*)d_ws;
    size_t off = 0;
    auto carve = [&](size_t bytes) -> char* {
        off = (off + 255) & ~(size_t)255;
        char* p = base + off;
        off += bytes;
        return p;
    };
    int* counts   = (int*)carve((size_t)N * 4);
    int* scanned  = (int*)carve((size_t)N * 4);
    int* bsums    = (int*)carve(256 * 4);
    int* row_off  = (int*)carve((size_t)(N + 1) * 4);
    int* rank     = (int*)carve((size_t)E * 4);
    int* csr_src  = (int*)carve((size_t)E * 4);
    u16* w1t_hi   = (u16*)carve(128 * 128 * 2);
    u16* w1t_lo   = (u16*)carve(128 * 128 * 2);
    u16* h1b      = (u16*)carve((size_t)N * 128 * 2);
    u32* out1b    = (u32*)carve((size_t)N * 16 * 4);
    float* as1  = (float*)carve((size_t)N * 4 * 4);
    float* ad1  = (float*)carve((size_t)N * 4 * 4);
    float* as2  = (float*)carve((size_t)N * 4 * 4);
    float* ad2  = (float*)carve((size_t)N * 4 * 4);
    float* w_as = (float*)carve(4 * 32 * 4);
    float* w_ad = (float*)carve(4 * 32 * 4);
    (void)ws_size; (void)n_in; (void)out_size;

    // --- CSR build + weight prep (fused grid) ---
    hipMemsetAsync(counts, 0, (size_t)N * 4, stream);
    int degBlocks = (E + 255) / 256;
    degree_prep_kernel<<<degBlocks + 65, 256, 0, stream>>>(dst, E, counts, rank,
                                                           W1, w1t_hi, w1t_lo,
                                                           W2, a2_src, a2_dst, w_as, w_ad,
                                                           degBlocks);
    int nb = (N + 1023) / 1024;
    scan_block_kernel<<<nb, 1024, 0, stream>>>(counts, N, scanned, bsums);
    scan_partials_kernel<<<1, 256, 0, stream>>>(bsums, nb);
    finalize_offsets_kernel<<<(N + 255) / 256, 256, 0, stream>>>(scanned, bsums, N, row_off);
    fill_csr_kernel<<<(E + 255) / 256, 256, 0, stream>>>(src, dst, E, row_off, rank, csr_src);

    // --- Layer 1 (GEMM + fused attn1) ---
    gemm1_mfma_kernel<<<(N + 63) / 64, 256, 0, stream>>>(x, w1t_hi, w1t_lo, a1_src, a1_dst,
                                                         h1b, as1, ad1, N);
    node_agg128_kernel<<<(N + 3) / 4, 256, 0, stream>>>((const u32*)h1b, as1, ad1,
                                                        row_off, csr_src, b1, w_as, w_ad,
                                                        out1b, as2, ad2, N);

    // --- Layer 2 (aggregate + fused W2 epilogue) ---
    node_agg32_fused_kernel<<<(N + 3) / 4, 256, 0, stream>>>(out1b, as2, ad2, row_off,
                                                             csr_src, W2, b2, out, N);
}

// Round 4
// 307.964 us; speedup vs baseline: 1.0794x; 1.0112x over previous
//
#include <hip/hip_runtime.h>
#include <math.h>

#define NEG_SLOPE 0.2f
#define EPS_GAT 1e-16f
#define LOG2E 1.4426950408889634f
typedef unsigned int u32;
typedef unsigned short u16;
typedef __attribute__((ext_vector_type(8))) short short8;   // 8 bf16 (4 VGPRs)
typedef __attribute__((ext_vector_type(4))) float f32x4;

// ---- bf16 helpers ----
__device__ inline u16 f2bf(float x) {
    union { float f; u32 u; } v; v.f = x;
    u32 r = v.u + 0x7FFFu + ((v.u >> 16) & 1u);   // RNE
    return (u16)(r >> 16);
}
__device__ inline float bf_lo(u32 u) {
    union { u32 i; float f; } v; v.i = u << 16; return v.f;
}
__device__ inline float bf_hi(u32 u) {
    union { u32 i; float f; } v; v.i = u & 0xFFFF0000u; return v.f;
}
__device__ inline float bf1(u16 s) {
    union { u32 i; float f; } v; v.i = ((u32)s) << 16; return v.f;
}
__device__ inline float fast_exp2(float x) {
#if __has_builtin(__builtin_amdgcn_exp2f)
    return __builtin_amdgcn_exp2f(x);
#else
    return exp2f(x);
#endif
}
// logits pre-scaled by LOG2E; lrelu commutes with positive scaling.
__device__ inline float lrelu_exp2(float t) {
    return fast_exp2(fmaxf(t, NEG_SLOPE * t));
}

// ---------------- CSR degree + (fused) weight prep ----------------
// blocks < degBlocks: degree+rank (one edge per thread). next 64: W1 hi/lo split. last: W2 fold.

__global__ void degree_prep_kernel(const int* __restrict__ dst, int E,
                                   int* __restrict__ counts, int* __restrict__ rank,
                                   const float* __restrict__ W1,
                                   u16* __restrict__ w1t_hi, u16* __restrict__ w1t_lo,
                                   const float* __restrict__ W2, const float* __restrict__ a2s,
                                   const float* __restrict__ a2d, float* __restrict__ w_as,
                                   float* __restrict__ w_ad, int degBlocks) {
    int b = blockIdx.x;
    if (b < degBlocks) {
        int e = b * 256 + threadIdx.x;
        if (e < E) rank[e] = atomicAdd(&counts[dst[e]], 1);
    } else if (b < degBlocks + 64) {
        int i = (b - degBlocks) * 256 + threadIdx.x;   // 16384
        int k = i >> 7, n = i & 127;
        float w = W1[i];
        u16 hi = f2bf(w);
        u16 lo = f2bf(w - bf1(hi));
        w1t_hi[n * 128 + k] = hi;
        w1t_lo[n * 128 + k] = lo;
    } else {
        int t = threadIdx.x;
        if (t < 128) {
            int h = t >> 5, k = t & 31;
            float s1 = 0.f, s2 = 0.f;
#pragma unroll
            for (int f = 0; f < 16; ++f) {
                float w = W2[k * 64 + h * 16 + f];
                s1 += w * a2s[h * 16 + f];
                s2 += w * a2d[h * 16 + f];
            }
            w_as[h * 32 + k] = s1;
            w_ad[h * 32 + k] = s2;
        }
    }
}

__global__ __launch_bounds__(1024) void scan_block_kernel(const int* __restrict__ counts, int N,
                                                          int* __restrict__ scanned, int* __restrict__ bsums) {
    __shared__ int tmp[1024];
    int i = blockIdx.x * 1024 + threadIdx.x;
    int v = (i < N) ? counts[i] : 0;
    tmp[threadIdx.x] = v;
    __syncthreads();
    for (int d = 1; d < 1024; d <<= 1) {
        int t = (threadIdx.x >= d) ? tmp[threadIdx.x - d] : 0;
        __syncthreads();
        tmp[threadIdx.x] += t;
        __syncthreads();
    }
    if (i < N) scanned[i] = tmp[threadIdx.x];
    if (threadIdx.x == 1023) bsums[blockIdx.x] = tmp[1023];
}

__global__ __launch_bounds__(256) void scan_partials_kernel(int* __restrict__ bsums, int nb) {
    __shared__ int tmp[256];
    int tid = threadIdx.x;
    int v = (tid < nb) ? bsums[tid] : 0;
    tmp[tid] = v;
    __syncthreads();
    for (int d = 1; d < 256; d <<= 1) {
        int t = (tid >= d) ? tmp[tid - d] : 0;
        __syncthreads();
        tmp[tid] += t;
        __syncthreads();
    }
    if (tid < nb) bsums[tid] = tmp[tid] - v;  // exclusive
}

__global__ void finalize_offsets_kernel(const int* __restrict__ scanned,
                                        const int* __restrict__ bsums_excl, int N,
                                        int* __restrict__ row_off) {
    int i = blockIdx.x * blockDim.x + threadIdx.x;
    if (i < N) {
        int incl = scanned[i] + bsums_excl[i >> 10];
        row_off[i + 1] = incl;
        if (i == 0) row_off[0] = 0;
    }
}

__global__ void fill_csr_kernel(const int* __restrict__ src, const int* __restrict__ dst, int E,
                                const int* __restrict__ row_off, const int* __restrict__ rank,
                                int* __restrict__ csr_src) {
    int e = blockIdx.x * blockDim.x + threadIdx.x;
    if (e < E) {
        int pos = row_off[dst[e]] + rank[e];
        csr_src[pos] = src[e];
    }
}

// ---------------- GEMM1 via MFMA + fused attn1 epilogue ----------------
// hi/lo split (3 MFMAs) = fp32-grade. After the K-loop, the h-tile is staged in
// LDS (aliasing the W-staging buffer — safe after the final barrier) and one
// thread per (row,head) computes the two 32-dots for as1/ad1 (pre-scaled LOG2E).

__global__ __launch_bounds__(256) void gemm1_mfma_kernel(const float* __restrict__ X,
                                                         const u16* __restrict__ w1t_hi,
                                                         const u16* __restrict__ w1t_lo,
                                                         const float* __restrict__ a_src,
                                                         const float* __restrict__ a_dst,
                                                         u16* __restrict__ Hb,
                                                         float* __restrict__ as_,
                                                         float* __restrict__ ad_, int N) {
    __shared__ u16 xsh_hi[64][40];
    __shared__ u16 xsh_lo[64][40];
    __shared__ u16 wbuf[10240];          // wsh_hi | wsh_lo; reused as h-tile after K-loop
    __shared__ float ash[128], adsh[128];
    u16* wsh_hi = wbuf;
    u16* wsh_lo = wbuf + 5120;
    int tid = threadIdx.x;
    int wave = tid >> 6, lane = tid & 63, quad = lane >> 4;
    int m0 = blockIdx.x * 64;

    if (tid < 128) { ash[tid] = a_src[tid]; adsh[tid] = a_dst[tid]; }

    f32x4 acc[4][2];
#pragma unroll
    for (int rt = 0; rt < 4; ++rt)
#pragma unroll
        for (int ct = 0; ct < 2; ++ct) acc[rt][ct] = (f32x4)(0.f);

    int xrow = tid >> 2, xkq = (tid & 3) * 8;

    for (int k0 = 0; k0 < 128; k0 += 32) {
        {
            int gr = m0 + xrow;
            float f[8];
            *(float4*)&f[0] = (gr < N) ? *(const float4*)(X + (size_t)gr * 128 + k0 + xkq)
                                       : make_float4(0.f, 0.f, 0.f, 0.f);
            *(float4*)&f[4] = (gr < N) ? *(const float4*)(X + (size_t)gr * 128 + k0 + xkq + 4)
                                       : make_float4(0.f, 0.f, 0.f, 0.f);
            u16 hi[8], lo[8];
#pragma unroll
            for (int i = 0; i < 8; ++i) {
                hi[i] = f2bf(f[i]);
                lo[i] = f2bf(f[i] - bf1(hi[i]));
            }
            *(uint4*)&xsh_hi[xrow][xkq] = *(uint4*)hi;
            *(uint4*)&xsh_lo[xrow][xkq] = *(uint4*)lo;
        }
        {
#pragma unroll
            for (int i = 0; i < 2; ++i) {
                int id = tid * 2 + i;
                int n = id >> 2, part = id & 3;
                *(uint4*)&wsh_hi[n * 40 + part * 8] =
                    ((const uint4*)(w1t_hi + n * 128 + k0))[part];
                *(uint4*)&wsh_lo[n * 40 + part * 8] =
                    ((const uint4*)(w1t_lo + n * 128 + k0))[part];
            }
        }
        __syncthreads();

        short8 bhi[2], blo[2];
#pragma unroll
        for (int ct = 0; ct < 2; ++ct) {
            int n = wave * 32 + ct * 16 + (lane & 15);
            bhi[ct] = *(const short8*)&wsh_hi[n * 40 + quad * 8];
            blo[ct] = *(const short8*)&wsh_lo[n * 40 + quad * 8];
        }
#pragma unroll
        for (int rt = 0; rt < 4; ++rt) {
            int m = rt * 16 + (lane & 15);
            short8 ahi = *(const short8*)&xsh_hi[m][quad * 8];
            short8 alo = *(const short8*)&xsh_lo[m][quad * 8];
#pragma unroll
            for (int ct = 0; ct < 2; ++ct) {
                acc[rt][ct] = __builtin_amdgcn_mfma_f32_16x16x32_bf16(ahi, bhi[ct], acc[rt][ct], 0, 0, 0);
                acc[rt][ct] = __builtin_amdgcn_mfma_f32_16x16x32_bf16(alo, bhi[ct], acc[rt][ct], 0, 0, 0);
                acc[rt][ct] = __builtin_amdgcn_mfma_f32_16x16x32_bf16(ahi, blo[ct], acc[rt][ct], 0, 0, 0);
            }
        }
        __syncthreads();
    }

    // h-tile -> global + LDS (stride 130 u16 per row; 16640 B <= 20480 B of wbuf)
    const int HS = 130;
#pragma unroll
    for (int rt = 0; rt < 4; ++rt)
#pragma unroll
        for (int ct = 0; ct < 2; ++ct) {
            int col = wave * 32 + ct * 16 + (lane & 15);
#pragma unroll
            for (int r = 0; r < 4; ++r) {
                int row = rt * 16 + quad * 4 + r;
                u16 hv = f2bf(acc[rt][ct][r]);
                int gr = m0 + row;
                if (gr < N) Hb[(size_t)gr * 128 + col] = hv;
                wbuf[row * HS + col] = hv;
            }
        }
    __syncthreads();

    // attn1: one thread per (row, head)
    {
        int row = tid >> 2, h = tid & 3;
        int gr = m0 + row;
        if (gr < N) {
            const u32* hr = (const u32*)&wbuf[row * HS + h * 32];   // 16 dwords
            float s1 = 0.f, s2 = 0.f;
#pragma unroll
            for (int q = 0; q < 16; ++q) {
                u32 u = hr[q];
                float flo = bf_lo(u), fhi = bf_hi(u);
                s1 += flo * ash[h * 32 + 2 * q] + fhi * ash[h * 32 + 2 * q + 1];
                s2 += flo * adsh[h * 32 + 2 * q] + fhi * adsh[h * 32 + 2 * q + 1];
            }
            as_[(size_t)gr * 4 + h] = s1 * LOG2E;
            ad_[(size_t)gr * 4 + h] = s2 * LOG2E;
        }
    }
}

// ---------------- layer-1 aggregate + fused attn2 epilogue ----------------
// R0-proven structure: per-lane redundant e (free — all 64 lanes must issue
// the FMA anyway; e-broadcast via same-line cached load = 1 txn/edge), now
// 8-deep unrolled: 8 as_ + 8 Hb loads in flight per wave (vs 4) halves the
// per-node waitcnt rounds. No shfl in the loop (R2/R3's shfl/e-hoisting added
// a serial vidx->shfl->as_->exp chain + DS traffic for zero txn savings and
// regressed 62->75->81us).

__global__ __launch_bounds__(256) void node_agg128_kernel(const u32* __restrict__ Hb,
                                                          const float* __restrict__ as_,
                                                          const float* __restrict__ ad_,
                                                          const int* __restrict__ row_off,
                                                          const int* __restrict__ csr_src,
                                                          const float* __restrict__ bias,
                                                          const float* __restrict__ w_as,
                                                          const float* __restrict__ w_ad,
                                                          u32* __restrict__ O1,
                                                          float* __restrict__ as2,
                                                          float* __restrict__ ad2, int N) {
    int lane = threadIdx.x & 63;
    int node = __builtin_amdgcn_readfirstlane(blockIdx.x * 4 + (threadIdx.x >> 6));
    if (node >= N) return;
    int start = __builtin_amdgcn_readfirstlane(row_off[node]);
    int end   = __builtin_amdgcn_readfirstlane(row_off[node + 1]);
    int deg = end - start;
    int h = lane >> 4;
    float adh = ad_[node * 4 + h];

    int clamp = (deg > 0) ? deg - 1 : 0;
    int vidx = (deg > 0) ? csr_src[start + min(lane, clamp)] : 0;
    int m = min(deg, 64);

    float2 acc = make_float2(0.f, 0.f);
    float den = 0.f;
    int j = 0;
    for (; j + 8 <= m; j += 8) {
        int sj[8];
#pragma unroll
        for (int k = 0; k < 8; ++k) sj[k] = __builtin_amdgcn_readlane(vidx, j + k);
        float aj[8];
#pragma unroll
        for (int k = 0; k < 8; ++k) aj[k] = as_[sj[k] * 4 + h];
        u32 uj[8];
#pragma unroll
        for (int k = 0; k < 8; ++k) uj[k] = Hb[(size_t)sj[k] * 64 + lane];
#pragma unroll
        for (int k = 0; k < 8; ++k) {
            float e = lrelu_exp2(aj[k] + adh);
            acc.x = fmaf(e, bf_lo(uj[k]), acc.x);
            acc.y = fmaf(e, bf_hi(uj[k]), acc.y);
            den += e;
        }
    }
    for (; j + 4 <= m; j += 4) {
        int s0 = __builtin_amdgcn_readlane(vidx, j);
        int s1 = __builtin_amdgcn_readlane(vidx, j + 1);
        int s2 = __builtin_amdgcn_readlane(vidx, j + 2);
        int s3 = __builtin_amdgcn_readlane(vidx, j + 3);
        float a0 = as_[s0 * 4 + h], a1 = as_[s1 * 4 + h];
        float a2 = as_[s2 * 4 + h], a3 = as_[s3 * 4 + h];
        u32 u0 = Hb[(size_t)s0 * 64 + lane];
        u32 u1 = Hb[(size_t)s1 * 64 + lane];
        u32 u2 = Hb[(size_t)s2 * 64 + lane];
        u32 u3 = Hb[(size_t)s3 * 64 + lane];
        float e0 = lrelu_exp2(a0 + adh), e1 = lrelu_exp2(a1 + adh);
        float e2 = lrelu_exp2(a2 + adh), e3 = lrelu_exp2(a3 + adh);
        acc.x = fmaf(e0, bf_lo(u0), acc.x); acc.y = fmaf(e0, bf_hi(u0), acc.y); den += e0;
        acc.x = fmaf(e1, bf_lo(u1), acc.x); acc.y = fmaf(e1, bf_hi(u1), acc.y); den += e1;
        acc.x = fmaf(e2, bf_lo(u2), acc.x); acc.y = fmaf(e2, bf_hi(u2), acc.y); den += e2;
        acc.x = fmaf(e3, bf_lo(u3), acc.x); acc.y = fmaf(e3, bf_hi(u3), acc.y); den += e3;
    }
    for (; j < m; ++j) {
        int s = __builtin_amdgcn_readlane(vidx, j);
        float e = lrelu_exp2(as_[s * 4 + h] + adh);
        u32 u = Hb[(size_t)s * 64 + lane];
        acc.x = fmaf(e, bf_lo(u), acc.x); acc.y = fmaf(e, bf_hi(u), acc.y); den += e;
    }
    for (int jj = start + 64; jj < end; ++jj) {   // deg>64 fallback
        int s = __builtin_amdgcn_readfirstlane(csr_src[jj]);
        float e = lrelu_exp2(as_[s * 4 + h] + adh);
        u32 u = Hb[(size_t)s * 64 + lane];
        acc.x = fmaf(e, bf_lo(u), acc.x); acc.y = fmaf(e, bf_hi(u), acc.y); den += e;
    }
    float inv = 1.f / (den + EPS_GAT);
    float px = acc.x * inv, py = acc.y * inv;
    // butterfly head-sum: afterwards EVERY lane holds the 4-head sum for f=lane&15
    px += __shfl_xor(px, 16); py += __shfl_xor(py, 16);
    px += __shfl_xor(px, 32); py += __shfl_xor(py, 32);

    int f2 = (lane & 15) * 2;
    float2 bv = *(const float2*)&bias[f2];
    float ox = fmaxf(px * 0.25f + bv.x, 0.f);
    float oy = fmaxf(py * 0.25f + bv.y, 0.f);
    if (lane < 16)
        O1[node * 16 + lane] = (u32)f2bf(ox) | ((u32)f2bf(oy) << 16);

    // fused attn2 (16-lane xor reduction)
    int h2 = lane >> 4;
    float2 wa = *(const float2*)&w_as[h2 * 32 + f2];
    float2 wd = *(const float2*)&w_ad[h2 * 32 + f2];
    float ta = ox * wa.x + oy * wa.y;
    float td = ox * wd.x + oy * wd.y;
    ta += __shfl_xor(ta, 1); td += __shfl_xor(td, 1);
    ta += __shfl_xor(ta, 2); td += __shfl_xor(td, 2);
    ta += __shfl_xor(ta, 4); td += __shfl_xor(td, 4);
    ta += __shfl_xor(ta, 8); td += __shfl_xor(td, 8);
    if ((lane & 15) == 0) {
        as2[node * 4 + h2] = ta * LOG2E;
        ad2[node * 4 + h2] = td * LOG2E;
    }
}

// ---------------- layer-2 aggregate + fused W2 epilogue ----------------
// R0-proven loop (per-lane e, now 8-unrolled) + barrier-free epilogue: W2 in
// LDS (one barrier at kernel start, before the node>=N return), epilogue via
// px/py shfl-broadcast + stride-1 ds_reads (2-way = conflict-free). No
// post-loop __syncthreads — the block's 4 nodes stay decoupled.

__global__ __launch_bounds__(256) void node_agg32_fused_kernel(const u32* __restrict__ O1,
                                                               const float* __restrict__ as_,
                                                               const float* __restrict__ ad_,
                                                               const int* __restrict__ row_off,
                                                               const int* __restrict__ csr_src,
                                                               const float* __restrict__ W2,
                                                               const float* __restrict__ b2,
                                                               float* __restrict__ Out, int N) {
    __shared__ float w2sh[2048];        // W2 [32][64]
    int tid = threadIdx.x;
    {
        float4 v = ((const float4*)W2)[tid];
        *(float4*)&w2sh[tid * 4] = v;
        float4 v2 = ((const float4*)W2)[tid + 256];
        *(float4*)&w2sh[(tid + 256) * 4] = v2;
    }
    __syncthreads();

    int lane = tid & 63;
    int h = lane >> 4, f = lane & 15;
    int grpbase = lane & 48;
    int node = __builtin_amdgcn_readfirstlane(blockIdx.x * 4 + (tid >> 6));
    if (node >= N) return;

    int start = __builtin_amdgcn_readfirstlane(row_off[node]);
    int end   = __builtin_amdgcn_readfirstlane(row_off[node + 1]);
    int deg = end - start;
    float adh = ad_[node * 4 + h];

    int clamp = (deg > 0) ? deg - 1 : 0;
    int vidx = (deg > 0) ? csr_src[start + min(lane, clamp)] : 0;
    int m = min(deg, 64);

    float2 acc = make_float2(0.f, 0.f);
    float den = 0.f;
    int j = 0;
    for (; j + 8 <= m; j += 8) {
        int sj[8];
#pragma unroll
        for (int k = 0; k < 8; ++k) sj[k] = __builtin_amdgcn_readlane(vidx, j + k);
        float aj[8];
#pragma unroll
        for (int k = 0; k < 8; ++k) aj[k] = as_[sj[k] * 4 + h];
        u32 uj[8];
#pragma unroll
        for (int k = 0; k < 8; ++k) uj[k] = O1[(size_t)sj[k] * 16 + f];
#pragma unroll
        for (int k = 0; k < 8; ++k) {
            float e = lrelu_exp2(aj[k] + adh);
            acc.x = fmaf(e, bf_lo(uj[k]), acc.x);
            acc.y = fmaf(e, bf_hi(uj[k]), acc.y);
            den += e;
        }
    }
    for (; j + 4 <= m; j += 4) {
        int s0 = __builtin_amdgcn_readlane(vidx, j);
        int s1 = __builtin_amdgcn_readlane(vidx, j + 1);
        int s2 = __builtin_amdgcn_readlane(vidx, j + 2);
        int s3 = __builtin_amdgcn_readlane(vidx, j + 3);
        float a0 = as_[s0 * 4 + h], a1 = as_[s1 * 4 + h];
        float a2 = as_[s2 * 4 + h], a3 = as_[s3 * 4 + h];
        u32 u0 = O1[(size_t)s0 * 16 + f];
        u32 u1 = O1[(size_t)s1 * 16 + f];
        u32 u2 = O1[(size_t)s2 * 16 + f];
        u32 u3 = O1[(size_t)s3 * 16 + f];
        float e0 = lrelu_exp2(a0 + adh), e1 = lrelu_exp2(a1 + adh);
        float e2 = lrelu_exp2(a2 + adh), e3 = lrelu_exp2(a3 + adh);
        acc.x = fmaf(e0, bf_lo(u0), acc.x); acc.y = fmaf(e0, bf_hi(u0), acc.y); den += e0;
        acc.x = fmaf(e1, bf_lo(u1), acc.x); acc.y = fmaf(e1, bf_hi(u1), acc.y); den += e1;
        acc.x = fmaf(e2, bf_lo(u2), acc.x); acc.y = fmaf(e2, bf_hi(u2), acc.y); den += e2;
        acc.x = fmaf(e3, bf_lo(u3), acc.x); acc.y = fmaf(e3, bf_hi(u3), acc.y); den += e3;
    }
    for (; j < m; ++j) {
        int s = __builtin_amdgcn_readlane(vidx, j);
        float e = lrelu_exp2(as_[s * 4 + h] + adh);
        u32 u = O1[(size_t)s * 16 + f];
        acc.x = fmaf(e, bf_lo(u), acc.x); acc.y = fmaf(e, bf_hi(u), acc.y); den += e;
    }
    for (int jj = start + 64; jj < end; ++jj) {
        int s = __builtin_amdgcn_readfirstlane(csr_src[jj]);
        float e = lrelu_exp2(as_[s * 4 + h] + adh);
        u32 u = O1[(size_t)s * 16 + f];
        acc.x = fmaf(e, bf_lo(u), acc.x); acc.y = fmaf(e, bf_hi(u), acc.y); den += e;
    }
    float inv = 1.f / (den + EPS_GAT);
    float px = acc.x * inv, py = acc.y * inv;

    // epilogue: s(h,f) = sum_k agg[h][k] * W2[k][h*16+f] via shfl broadcast
    float s = 0.f;
#pragma unroll
    for (int k = 0; k < 16; ++k) {
        float vx = __shfl(px, grpbase | k);
        float vy = __shfl(py, grpbase | k);
        s = fmaf(vx, w2sh[(2 * k) * 64 + lane], s);
        s = fmaf(vy, w2sh[(2 * k + 1) * 64 + lane], s);
    }
    s += __shfl_xor(s, 16);
    s += __shfl_xor(s, 32);
    if (lane < 16)
        Out[(size_t)node * 16 + f] = s * 0.25f + b2[f];
}

// ---------------- launch ----------------

extern "C" void kernel_launch(void* const* d_in, const int* in_sizes, int n_in,
                              void* d_out, int out_size, void* d_ws, size_t ws_size,
                              hipStream_t stream) {
    const float* x      = (const float*)d_in[0];
    const int*   eidx   = (const int*)d_in[1];
    const float* W1     = (const float*)d_in[2];
    const float* a1_src = (const float*)d_in[3];
    const float* a1_dst = (const float*)d_in[4];
    const float* b1     = (const float*)d_in[5];
    const float* W2     = (const float*)d_in[6];
    const float* a2_src = (const float*)d_in[7];
    const float* a2_dst = (const float*)d_in[8];
    const float* b2     = (const float*)d_in[9];
    float* out = (float*)d_out;

    const int N = in_sizes[0] / 128;
    const int E = in_sizes[1] / 2;
    const int* src = eidx;
    const int* dst = eidx + E;

    char* base = (char*)d_ws;
    size_t off = 0;
    auto carve = [&](size_t bytes) -> char* {
        off = (off + 255) & ~(size_t)255;
        char* p = base + off;
        off += bytes;
        return p;
    };
    int* counts   = (int*)carve((size_t)N * 4);
    int* scanned  = (int*)carve((size_t)N * 4);
    int* bsums    = (int*)carve(256 * 4);
    int* row_off  = (int*)carve((size_t)(N + 1) * 4);
    int* rank     = (int*)carve((size_t)E * 4);
    int* csr_src  = (int*)carve((size_t)E * 4);
    u16* w1t_hi   = (u16*)carve(128 * 128 * 2);
    u16* w1t_lo   = (u16*)carve(128 * 128 * 2);
    u16* h1b      = (u16*)carve((size_t)N * 128 * 2);
    u32* out1b    = (u32*)carve((size_t)N * 16 * 4);
    float* as1  = (float*)carve((size_t)N * 4 * 4);
    float* ad1  = (float*)carve((size_t)N * 4 * 4);
    float* as2  = (float*)carve((size_t)N * 4 * 4);
    float* ad2  = (float*)carve((size_t)N * 4 * 4);
    float* w_as = (float*)carve(4 * 32 * 4);
    float* w_ad = (float*)carve(4 * 32 * 4);
    (void)ws_size; (void)n_in; (void)out_size;

    // --- CSR build + weight prep (fused grid) ---
    hipMemsetAsync(counts, 0, (size_t)N * 4, stream);
    int degBlocks = (E + 255) / 256;
    degree_prep_kernel<<<degBlocks + 65, 256, 0, stream>>>(dst, E, counts, rank,
                                                           W1, w1t_hi, w1t_lo,
                                                           W2, a2_src, a2_dst, w_as, w_ad,
                                                           degBlocks);
    int nb = (N + 1023) / 1024;
    scan_block_kernel<<<nb, 1024, 0, stream>>>(counts, N, scanned, bsums);
    scan_partials_kernel<<<1, 256, 0, stream>>>(bsums, nb);
    finalize_offsets_kernel<<<(N + 255) / 256, 256, 0, stream>>>(scanned, bsums, N, row_off);
    fill_csr_kernel<<<(E + 255) / 256, 256, 0, stream>>>(src, dst, E, row_off, rank, csr_src);

    // --- Layer 1 (GEMM + fused attn1) ---
    gemm1_mfma_kernel<<<(N + 63) / 64, 256, 0, stream>>>(x, w1t_hi, w1t_lo, a1_src, a1_dst,
                                                         h1b, as1, ad1, N);
    node_agg128_kernel<<<(N + 3) / 4, 256, 0, stream>>>((const u32*)h1b, as1, ad1,
                                                        row_off, csr_src, b1, w_as, w_ad,
                                                        out1b, as2, ad2, N);

    // --- Layer 2 (aggregate + fused W2 epilogue) ---
    node_agg32_fused_kernel<<<(N + 3) / 4, 256, 0, stream>>>(out1b, as2, ad2, row_off,
                                                             csr_src, W2, b2, out, N);
}